// Round 13
// baseline (157.278 us; speedup 1.0000x reference)
//
#include <hip/hip_runtime.h>
#include <hip/hip_bf16.h>
#include <math.h>

#define TT 1024
#define HH 1024
#define NEXP 16
#define NI 704
#define SI 2048
#define UPMAX 448             // max up tiles: 16*6*4 routed + 64 shared
#define WDTILES 1408          // wd transpose tiles (64r x 128c) fused into k_up grid
#define DNSHARED 64           // shared down blocks (8 mt x 8 nt, K=2048)
#define DNMAX (DNSHARED + 504)

typedef unsigned short us;
typedef __attribute__((ext_vector_type(8))) __bf16 bf16x8;
typedef __attribute__((ext_vector_type(4))) float f32x4;
typedef __attribute__((ext_vector_type(4))) unsigned short us4;

__device__ __forceinline__ us f2bf(float f) {
  unsigned u = __builtin_bit_cast(unsigned, f);
  u += 0x7fffu + ((u >> 16) & 1u);   // RNE
  return (us)(u >> 16);
}

// r12-style swizzle for 64B-row tiles ([rows][32bf16], BK=32 k_down path)
__device__ __forceinline__ int ldsOff(int row, int kg) {
  return (row * 4 + (kg ^ ((row >> 1) & 3))) * 16;
}

__device__ __forceinline__ void gl16(const void* g, void* l) {
  __builtin_amdgcn_global_load_lds((const __attribute__((address_space(1))) void*)g,
                                   (__attribute__((address_space(3))) void*)l, 16, 0, 0);
}

// m204 bijective XCD-chunk map
__device__ __forceinline__ int chunkMap(int b, int n) {
  int q = n >> 3, r = n & 7;
  int c = b & 7, i = b >> 3;
  int base = (c < r) ? c * (q + 1) : r * (q + 1) + (c - r) * q;
  return base + i;
}

// ---------------- 256-thread transpose+convert tile (64x64) ----------------
__device__ __forceinline__ void tconv_tile(const float* __restrict__ inz,
                                           us* __restrict__ outz,
                                           int C, int ldo, int r0, int c0,
                                           float (*tile)[65]) {
  int t = threadIdx.x;
  int rr = t >> 4, cc = (t & 15) * 4;
  #pragma unroll
  for (int i = 0; i < 4; ++i) {
    f32x4 v = *reinterpret_cast<const f32x4*>(inz + (size_t)(r0 + rr + i * 16) * C + c0 + cc);
    tile[rr + i*16][cc + 0] = v[0];
    tile[rr + i*16][cc + 1] = v[1];
    tile[rr + i*16][cc + 2] = v[2];
    tile[rr + i*16][cc + 3] = v[3];
  }
  __syncthreads();
  int c = t >> 2, rq = t & 3;
  us o0[8], o1[8];
  #pragma unroll
  for (int j = 0; j < 8; ++j) {
    o0[j] = f2bf(tile[rq * 16 + j][c]);
    o1[j] = f2bf(tile[rq * 16 + 8 + j][c]);
  }
  us* op = outz + (size_t)(c0 + c) * ldo + r0 + rq * 16;
  *reinterpret_cast<us4*>(op)      = *reinterpret_cast<us4*>(&o0[0]);
  *reinterpret_cast<us4*>(op + 4)  = *reinterpret_cast<us4*>(&o0[4]);
  *reinterpret_cast<us4*>(op + 8)  = *reinterpret_cast<us4*>(&o1[0]);
  *reinterpret_cast<us4*>(op + 12) = *reinterpret_cast<us4*>(&o1[4]);
}

// ---------------- 512-thread transpose+convert (64 rows x 128 cols) ----------------
__device__ __forceinline__ void tconv512(const float* __restrict__ inz,
                                         us* __restrict__ outz,
                                         int i0, int h0, float (*tile)[129]) {
  int t = threadIdx.x;
  int ir = t >> 3, cg = (t & 7) * 4;
  #pragma unroll
  for (int p = 0; p < 4; ++p) {
    f32x4 v = *reinterpret_cast<const f32x4*>(inz + (size_t)(i0 + ir) * HH + h0 + cg + p * 32);
    tile[ir][cg + p*32 + 0] = v[0];
    tile[ir][cg + p*32 + 1] = v[1];
    tile[ir][cg + p*32 + 2] = v[2];
    tile[ir][cg + p*32 + 3] = v[3];
  }
  __syncthreads();
  int c = t >> 2, rq = t & 3;
  us o[16];
  #pragma unroll
  for (int j = 0; j < 16; ++j) o[j] = f2bf(tile[rq * 16 + j][c]);
  us* op = outz + (size_t)(h0 + c) * NI + i0 + rq * 16;
  *reinterpret_cast<us4*>(op)      = *reinterpret_cast<us4*>(&o[0]);
  *reinterpret_cast<us4*>(op + 4)  = *reinterpret_cast<us4*>(&o[4]);
  *reinterpret_cast<us4*>(op + 8)  = *reinterpret_cast<us4*>(&o[8]);
  *reinterpret_cast<us4*>(op + 12) = *reinterpret_cast<us4*>(&o[12]);
}

// ---------------- prep: gate + h->bf16 + up-weight tconv, fused ----------------
__global__ __launch_bounds__(256) void k_prep(
    const float* __restrict__ h, const float* __restrict__ gw,
    const float* __restrict__ bias, float* __restrict__ cw,
    us* __restrict__ hb, unsigned* __restrict__ selpk,
    const float* __restrict__ wg, const float* __restrict__ wu,
    const float* __restrict__ swg, const float* __restrict__ swu,
    us* __restrict__ wgb, us* __restrict__ wub,
    us* __restrict__ swgb, us* __restrict__ swub) {
  __shared__ float tile[64][65];
  __shared__ float lgS[NEXP];
  int b = blockIdx.x;
  int tid = threadIdx.x;
  if (b < 1024) {
    int t = b;
    const float* hr = h + (size_t)t * HH;
    {
      f32x4 v = *reinterpret_cast<const f32x4*>(hr + tid * 4);
      us4 p;
      p[0] = f2bf(v[0]); p[1] = f2bf(v[1]); p[2] = f2bf(v[2]); p[3] = f2bf(v[3]);
      *reinterpret_cast<us4*>(hb + (size_t)t * HH + tid * 4) = p;
    }
    int e = tid >> 4, sub = tid & 15;
    const f32x4* hr4 = reinterpret_cast<const f32x4*>(hr);
    const f32x4* gr4 = reinterpret_cast<const f32x4*>(gw + (size_t)e * HH);
    float acc = 0.f;
    for (int i = sub; i < 256; i += 16) {
      f32x4 a = hr4[i], g = gr4[i];
      acc += a[0]*g[0] + a[1]*g[1] + a[2]*g[2] + a[3]*g[3];
    }
    acc += __shfl_down(acc, 8, 16);
    acc += __shfl_down(acc, 4, 16);
    acc += __shfl_down(acc, 2, 16);
    acc += __shfl_down(acc, 1, 16);
    if (sub == 0) lgS[e] = acc;
    __syncthreads();
    if (tid == 0) {
      float sc[NEXP], s4[NEXP];
      for (int i = 0; i < NEXP; ++i) {
        sc[i] = 1.f / (1.f + expf(-lgS[i]));
        s4[i] = sc[i] + bias[i];
      }
      float gs[4];
      for (int g = 0; g < 4; ++g) {
        float a = s4[4*g], bb = s4[4*g+1], c = s4[4*g+2], d = s4[4*g+3];
        float mx01 = fmaxf(a, bb), mn01 = fminf(a, bb);
        float mx23 = fmaxf(c, d), mn23 = fminf(c, d);
        float top = fmaxf(mx01, mx23);
        float sec = (mx01 >= mx23) ? fmaxf(mn01, mx23) : fmaxf(mn23, mx01);
        gs[g] = top + sec;
      }
      int g1 = 0;
      for (int g = 1; g < 4; ++g) if (gs[g] > gs[g1]) g1 = g;
      int g2 = -1;
      for (int g = 0; g < 4; ++g) { if (g == g1) continue; if (g2 < 0 || gs[g] > gs[g2]) g2 = g; }
      int sel[6];
      bool used[NEXP];
      for (int i = 0; i < NEXP; ++i) used[i] = false;
      float wsum = 0.f;
      for (int it = 0; it < 6; ++it) {
        int best = -1; float bv = 0.f;
        for (int i = 0; i < NEXP; ++i) {
          int grp = i >> 2;
          if ((grp != g1 && grp != g2) || used[i]) continue;
          if (best < 0 || s4[i] > bv) { best = i; bv = s4[i]; }
        }
        used[best] = true;
        sel[it] = best;
        wsum += sc[best];
      }
      float inv = 2.0f / wsum;   // ROUTED_SCALE folded
      unsigned pk = 0;
      for (int it = 0; it < 6; ++it) {
        pk |= (unsigned)sel[it] << (it * 4);
        cw[(size_t)t * NEXP + sel[it]] = sc[sel[it]] * inv;
      }
      selpk[t] = pk;
    }
    return;
  }
  b -= 1024;
  if (b < 2816) {        // wg
    int z = b / 176, r = b % 176;
    tconv_tile(wg + (size_t)z * HH * NI, wgb + (size_t)z * NI * HH,
               NI, HH, (r / 11) * 64, (r % 11) * 64, tile);
    return;
  }
  b -= 2816;
  if (b < 2816) {        // wu
    int z = b / 176, r = b % 176;
    tconv_tile(wu + (size_t)z * HH * NI, wub + (size_t)z * NI * HH,
               NI, HH, (r / 11) * 64, (r % 11) * 64, tile);
    return;
  }
  b -= 2816;
  if (b < 512) {         // swg
    tconv_tile(swg, swgb, SI, HH, (b >> 5) * 64, (b & 31) * 64, tile);
    return;
  }
  b -= 512;
  {                      // swu
    tconv_tile(swu, swub, SI, HH, (b >> 5) * 64, (b & 31) * 64, tile);
  }
}

// ------- list build + compact work lists (up: 256-row tiles, down: 128-row) -------
__global__ void k_scan(const unsigned* __restrict__ selpk,
                       int* __restrict__ cnt, int* __restrict__ list,
                       int* __restrict__ wlUp, int* __restrict__ wlDn,
                       int* __restrict__ totals) {
  int t = threadIdx.x;           // token
  int w = t >> 6, l = t & 63;
  unsigned pk = selpk[t];
  unsigned short flags = 0;
  #pragma unroll
  for (int j = 0; j < 6; ++j) flags |= (unsigned short)(1u << ((pk >> (j * 4)) & 15));
  __shared__ int wc[16][16];
  __shared__ int pre[16][16];
  __shared__ int t128[16], t256[16], upo[16], dno[16], totR[2];
  #pragma unroll
  for (int e = 0; e < 16; ++e) {
    unsigned long long bal = __ballot((flags >> e) & 1);
    if (l == 0) wc[w][e] = __popcll(bal);
  }
  __syncthreads();
  if (t < 16) {                  // t = expert
    int s = 0;
    for (int ww = 0; ww < 16; ++ww) { pre[ww][t] = s; s += wc[ww][t]; }
    cnt[t] = s;
    t128[t] = (s + 127) >> 7;
    t256[t] = (s + 255) >> 8;
  }
  __syncthreads();
  if (t < 16) {
    int uo = 0, dn = 0;
    for (int e2 = 0; e2 < t; ++e2) { uo += 6 * t256[e2]; dn += 8 * t128[e2]; }
    upo[t] = uo; dno[t] = dn;
    if (t == 15) { totR[0] = uo + 6 * t256[15]; totR[1] = dn + 8 * t128[15]; }
  }
  __syncthreads();
  {
    int teU = t256[w];
    for (int i = l; i < 6 * teU; i += 64) {
      int nt = i / teU, mt = i - nt * teU;
      wlUp[upo[w] + i] = ((w * 6 + nt) << 3) | mt;
    }
    int teD = t128[w];
    for (int i = l; i < 8 * teD; i += 64) {
      int nt = i / teD, mt = i - nt * teD;
      wlDn[dno[w] + i] = ((w * 8 + nt) << 3) | mt;
    }
  }
  if (w == 0) {
    for (int j = l; j < 64; j += 64)               // shared up: 16 nt x 4 mt
      wlUp[totR[0] + j] = ((96 + (j >> 2)) << 3) | (j & 3);
  }
  if (t == 0) { totals[0] = totR[0] + 64; totals[1] = totR[1]; }
  unsigned long long lmask = (l == 0) ? 0ull : ((~0ull) >> (64 - l));
  #pragma unroll
  for (int e = 0; e < 16; ++e) {
    bool f = (flags >> e) & 1;
    unsigned long long bal = __ballot(f);
    if (f) {
      int rank = __popcll(bal & lmask);
      int j = 0;
      #pragma unroll
      for (int jj = 0; jj < 6; ++jj) j += (((pk >> (jj * 4)) & 15) == (unsigned)e) ? jj : 0;
      list[(e << 10) + pre[w][e] + rank] = (t << 3) | j;
    }
  }
}

// ---------------- swd transpose (aliases swgb, runs after k_upT) ----------------
__global__ void k_tconvS(const float* __restrict__ swd, us* __restrict__ swdT) {
  __shared__ float tile[64][65];
  int b = blockIdx.x;
  tconv_tile(swd, swdT, HH, SI, (b >> 4) * 64, (b & 15) * 64, tile);
}

// ------- up: 256M x 128N dual-GEMM, 8 waves, wave=128x32, BK=32,
//         ONE vmcnt+barrier per k-tile (32 dual-MFMA/wave/sync) + fused wd-tconv -------
__global__ __launch_bounds__(512) void k_upT(
    const us* __restrict__ hb,
    const us* __restrict__ wgb, const us* __restrict__ wub,
    const us* __restrict__ swgb, const us* __restrict__ swub,
    const float* __restrict__ cw, const int* __restrict__ list,
    const int* __restrict__ cnt, const int* __restrict__ wlUp,
    const int* __restrict__ totals,
    us* __restrict__ cact_r, us* __restrict__ cact_s,
    const float* __restrict__ wd, us* __restrict__ wdbT) {
  __shared__ __align__(16) char ldsb[65536];   // 2 x (A 16K | Bg 8K | Bu 8K)
  int tid = threadIdx.x;
  if ((int)blockIdx.x >= UPMAX) {
    int b = blockIdx.x - UPMAX;
    int z = b / 88, r = b % 88;
    tconv512(wd + (size_t)z * NI * HH, wdbT + (size_t)z * HH * NI,
             (r >> 3) * 64, (r & 7) * 128,
             reinterpret_cast<float(*)[129]>(ldsb));
    return;
  }
  int tot = totals[0];
  if ((int)blockIdx.x >= tot) return;
  int item = wlUp[chunkMap(blockIdx.x, tot)];
  int group = item >> 3, mt = item & 7;
  int t0 = mt * 256;
  bool routed = group < 96;
  int e = 0, n0, cntE = TT;
  const us *bgBase, *buBase;
  if (routed) {
    e = group / 6;
    n0 = (group - e * 6) * 128;
    cntE = cnt[e];
    bgBase = wgb + (size_t)e * NI * HH;
    buBase = wub + (size_t)e * NI * HH;
  } else {
    n0 = (group - 96) * 128;
    bgBase = swgb;
    buBase = swub;
  }
  int w = tid >> 6, l = tid & 63;
  int wm = w >> 2, wn = w & 3;      // 2 (M) x 4 (N) waves; wave = 128M x 32N per matrix
  int lr = l & 15, lg2 = l >> 4;

  // ---- stage sources: 4 x 16B chunks per thread per k-tile ----
  // chunk ci -> row=ci>>2, dest slot=ci&3; source kg = slot ^ (row&3)  (2-way = free)
  const us *s0, *s1, *s2, *s3;
  {
    int row0 = tid >> 2;
    int kgA = (tid & 3) ^ (row0 & 3);
    int sl0 = t0 + row0;
    int tok0 = routed ? ((sl0 < cntE) ? (list[(e << 10) + sl0] >> 3) : 0) : sl0;
    s0 = hb + (size_t)tok0 * HH + kgA * 8;
    int sl1 = sl0 + 128;
    int tok1 = routed ? ((sl1 < cntE) ? (list[(e << 10) + sl1] >> 3) : 0) : sl1;
    s1 = hb + (size_t)tok1 * HH + kgA * 8;
    int brow = n0 + row0;
    if (routed && brow >= NI) brow = NI - 1;
    s2 = bgBase + (size_t)brow * HH + kgA * 8;
    s3 = buBase + (size_t)brow * HH + kgA * 8;
  }
  int wslot = w * 1024;
  auto stageAll = [&](char* buf) {
    gl16(s0, buf + wslot);             // A rows 0..127
    gl16(s1, buf + 8192 + wslot);      // A rows 128..255
    gl16(s2, buf + 16384 + wslot);     // Bg
    gl16(s3, buf + 24576 + wslot);     // Bu
    s0 += 32; s1 += 32; s2 += 32; s3 += 32;
  };

  f32x4 accG[8][2] = {};
  f32x4 accU[8][2] = {};

  // lane-constant read offsets: row&3 == lr&3
  int sw16 = (lg2 ^ (lr & 3)) * 16;
  int aoff = lr * 64 + sw16;           // within A region (row*64)
  int boff = lr * 64 + sw16;

  char* cur = ldsb;
  char* nxt = ldsb + 32768;
  stageAll(cur);
  asm volatile("s_waitcnt vmcnt(0)" ::: "memory");
  __builtin_amdgcn_s_barrier();
  asm volatile("" ::: "memory");

  for (int t = 0; t < 32; ++t) {
    if (t < 31) stageAll(nxt);
    bf16x8 af[8], bg[2], bu[2];
    #pragma unroll
    for (int rf = 0; rf < 8; ++rf)
      af[rf] = *reinterpret_cast<const bf16x8*>(cur + (wm * 128 + rf * 16) * 64 + aoff);
    #pragma unroll
    for (int cf = 0; cf < 2; ++cf) {
      int rb = (wn * 32 + cf * 16) * 64 + boff;
      bg[cf] = *reinterpret_cast<const bf16x8*>(cur + 16384 + rb);
      bu[cf] = *reinterpret_cast<const bf16x8*>(cur + 24576 + rb);
    }
    #pragma unroll
    for (int rf = 0; rf < 8; ++rf)
      #pragma unroll
      for (int cf = 0; cf < 2; ++cf) {
        accG[rf][cf] = __builtin_amdgcn_mfma_f32_16x16x32_bf16(af[rf], bg[cf], accG[rf][cf], 0, 0, 0);
        accU[rf][cf] = __builtin_amdgcn_mfma_f32_16x16x32_bf16(af[rf], bu[cf], accU[rf][cf], 0, 0, 0);
      }
    asm volatile("s_waitcnt vmcnt(0)" ::: "memory");
    __builtin_amdgcn_s_barrier();
    asm volatile("" ::: "memory");
    char* tp = cur; cur = nxt; nxt = tp;
  }

  #pragma unroll
  for (int rf = 0; rf < 8; ++rf)
    #pragma unroll
    for (int cf = 0; cf < 2; ++cf)
      #pragma unroll
      for (int r = 0; r < 4; ++r) {
        int row = wm * 128 + rf * 16 + lg2 * 4 + r;
        int col = wn * 32 + cf * 16 + lr;
        float g = accG[rf][cf][r], u = accU[rf][cf][r];
        float act = g / (1.f + __expf(-g)) * u;
        if (routed) {
          int slot = t0 + row;
          if (slot < cntE && n0 + col < NI) {
            int packed = list[(e << 10) + slot];
            float scl = cw[(size_t)(packed >> 3) * NEXP + e];
            cact_r[((size_t)(e << 10) + slot) * NI + n0 + col] = f2bf(act * scl);
          }
        } else {
          cact_s[(size_t)(t0 + row) * SI + n0 + col] = f2bf(act);
        }
      }
}

// ------- down: [0,64) shared K=2048 -> out direct; rest routed -> bf16 part[t][j] -------
__global__ __launch_bounds__(256) void k_down(
    const us* __restrict__ cact_r, const us* __restrict__ cact_s,
    const us* __restrict__ wdbT, const us* __restrict__ swdT,
    const int* __restrict__ list, const int* __restrict__ cnt,
    const int* __restrict__ wlDn, const int* __restrict__ totals,
    us* __restrict__ part, float* __restrict__ out) {
  __shared__ __align__(16) char ldsb[32768];
  int tid = threadIdx.x;
  int b = blockIdx.x;
  bool routed;
  int e = 0, nt, mt, kiter, Ksrc, cntE = TT;
  const us *Ab, *Bb;
  if (b < DNSHARED) {
    routed = false;
    nt = b & 7;
    mt = b >> 3;
    kiter = 64;
    Ksrc = SI;
    Ab = cact_s;
    Bb = swdT;
  } else {
    routed = true;
    int rb = b - DNSHARED;
    int tot = totals[1];
    if (rb >= tot) return;
    int item = wlDn[chunkMap(rb, tot)];
    int group = item >> 3;
    mt = item & 7;
    e = group >> 3; nt = group & 7;
    cntE = cnt[e];
    kiter = NI / 32;
    Ksrc = NI;
    Ab = cact_r + (size_t)e * 1024 * NI;
    Bb = wdbT + (size_t)e * 1024 * NI;
  }
  int t0 = mt * 128;
  int n0 = nt * 128;
  int w = tid >> 6, l = tid & 63;
  int wm = w >> 1, wn = w & 1;
  int lr = l & 15, lg2 = l >> 4;

  int rowA = tid >> 2;
  int kg = (tid & 3) ^ ((rowA >> 1) & 3);
  const us* aS0 = Ab + (size_t)(t0 + rowA) * Ksrc + kg * 8;
  const us* aS1 = Ab + (size_t)(t0 + 64 + rowA) * Ksrc + kg * 8;
  const us* bS0 = Bb + (size_t)(n0 + rowA) * Ksrc + kg * 8;
  const us* bS1 = Bb + (size_t)(n0 + 64 + rowA) * Ksrc + kg * 8;

  f32x4 acc[4][4] = {};

  int wslot = w * 1024;
  auto stage = [&](char* buf) {
    char* bp = buf + wslot;
    gl16(aS0, bp);
    gl16(aS1, bp + 4096);
    gl16(bS0, bp + 8192);
    gl16(bS1, bp + 12288);
    aS0 += 32; aS1 += 32; bS0 += 32; bS1 += 32;
  };

  char* bufR = ldsb;
  char* bufW = ldsb + 16384;
  stage(bufR);
  __syncthreads();
  for (int ki = 0; ki < kiter; ++ki) {
    if (ki + 1 < kiter) stage(bufW);
    bf16x8 af[4], bb[4];
    #pragma unroll
    for (int rf = 0; rf < 4; ++rf)
      af[rf] = *reinterpret_cast<const bf16x8*>(bufR + ldsOff(wm * 64 + rf * 16 + lr, lg2));
    #pragma unroll
    for (int cf = 0; cf < 4; ++cf)
      bb[cf] = *reinterpret_cast<const bf16x8*>(bufR + 8192 + ldsOff(wn * 64 + cf * 16 + lr, lg2));
    #pragma unroll
    for (int rf = 0; rf < 4; ++rf)
      #pragma unroll
      for (int cf = 0; cf < 4; ++cf)
        acc[rf][cf] = __builtin_amdgcn_mfma_f32_16x16x32_bf16(af[rf], bb[cf], acc[rf][cf], 0, 0, 0);
    __syncthreads();
    char* tp = bufR; bufR = bufW; bufW = tp;
  }
  #pragma unroll
  for (int rf = 0; rf < 4; ++rf)
    #pragma unroll
    for (int cf = 0; cf < 4; ++cf)
      #pragma unroll
      for (int r = 0; r < 4; ++r) {
        int row = wm * 64 + rf * 16 + lg2 * 4 + r;
        int col = wn * 64 + cf * 16 + lr;
        if (routed) {
          int slot = t0 + row;
          if (slot < cntE) {
            int packed = list[(e << 10) + slot];
            int t = packed >> 3, j = packed & 7;
            part[((size_t)t * 6 + j) * 1024 + n0 + col] = f2bf(acc[rf][cf][r]);
          }
        } else {
          out[(size_t)(t0 + row) * HH + n0 + col] = acc[rf][cf][r];
        }
      }
}

__global__ void k_reduce(const us* __restrict__ part, float* __restrict__ out) {
  int i = (blockIdx.x * blockDim.x + threadIdx.x) * 4;
  int t = i >> 10, hh = i & 1023;
  f32x4 s = *reinterpret_cast<const f32x4*>(out + i);
  #pragma unroll
  for (int j = 0; j < 6; ++j) {
    us4 p = *reinterpret_cast<const us4*>(part + ((size_t)t * 6 + j) * 1024 + hh);
    #pragma unroll
    for (int k = 0; k < 4; ++k)
      s[k] += __builtin_bit_cast(float, (unsigned)p[k] << 16);
  }
  *reinterpret_cast<f32x4*>(out + i) = s;
}

// ---- workspace layout (total ~102.2 MiB) ----
#define HB_OFF    0ULL
#define CW_OFF    2097152ULL
#define CNT_OFF   2162688ULL
#define SELPK_OFF 2166784ULL
#define LIST_OFF  2170880ULL
#define WLUP_OFF  2236416ULL
#define WLDN_OFF  2244608ULL
#define TOT_OFF   2252800ULL
#define CACTR_OFF 2260992ULL           // 23.07 MB [16*1024][704] bf16
#define CACTS_OFF 25329664ULL          // 4 MB [1024][2048] bf16
#define WGB_OFF   29523968ULL          // 23.07 MB (dead after k_upT)
#define WUB_OFF   52592640ULL          // 23.07 MB (dead after k_upT)
#define SWGB_OFF  75661312ULL          // 4 MB (dead after k_upT)
#define SWUB_OFF  79855616ULL          // 4 MB (dead after k_upT)
#define WDBT_OFF  84049920ULL          // 22.53 MB disjoint (written DURING k_upT)
#define SWDT_OFF  SWGB_OFF
#define PART_OFF  WGB_OFF              // 12 MB [1024][6][1024] bf16

extern "C" void kernel_launch(void* const* d_in, const int* in_sizes, int n_in,
                              void* d_out, int out_size, void* d_ws, size_t ws_size,
                              hipStream_t stream) {
  const float* h    = (const float*)d_in[0];
  const float* gw   = (const float*)d_in[1];
  const float* bias = (const float*)d_in[2];
  const float* wg   = (const float*)d_in[3];
  const float* wu   = (const float*)d_in[4];
  const float* wd   = (const float*)d_in[5];
  const float* swg  = (const float*)d_in[6];
  const float* swu  = (const float*)d_in[7];
  const float* swd  = (const float*)d_in[8];
  float* out = (float*)d_out;

  char* ws = (char*)d_ws;
  us*       hb     = (us*)(ws + HB_OFF);
  float*    cw     = (float*)(ws + CW_OFF);
  int*      cnt    = (int*)(ws + CNT_OFF);
  unsigned* selpk  = (unsigned*)(ws + SELPK_OFF);
  int*      list   = (int*)(ws + LIST_OFF);
  int*      wlUp   = (int*)(ws + WLUP_OFF);
  int*      wlDn   = (int*)(ws + WLDN_OFF);
  int*      totals = (int*)(ws + TOT_OFF);
  us*       cact_r = (us*)(ws + CACTR_OFF);
  us*       cact_s = (us*)(ws + CACTS_OFF);
  us*       wgb    = (us*)(ws + WGB_OFF);
  us*       wub    = (us*)(ws + WUB_OFF);
  us*       swgb   = (us*)(ws + SWGB_OFF);
  us*       swub   = (us*)(ws + SWUB_OFF);
  us*       wdbT   = (us*)(ws + WDBT_OFF);
  us*       swdT   = (us*)(ws + SWDT_OFF);
  us*       part   = (us*)(ws + PART_OFF);

  k_prep<<<7680, 256, 0, stream>>>(h, gw, bias, cw, hb, selpk,
                                   wg, wu, swg, swu, wgb, wub, swgb, swub);
  k_scan<<<1, 1024, 0, stream>>>(selpk, cnt, list, wlUp, wlDn, totals);

  k_upT<<<UPMAX + WDTILES, 512, 0, stream>>>(hb, wgb, wub, swgb, swub, cw, list,
                                             cnt, wlUp, totals, cact_r, cact_s,
                                             wd, wdbT);

  k_tconvS<<<512, 256, 0, stream>>>(swd, swdT);

  k_down<<<DNMAX, 256, 0, stream>>>(cact_r, cact_s, wdbT, swdT, list, cnt,
                                    wlDn, totals, part, out);
  k_reduce<<<1024, 256, 0, stream>>>(part, out);
}

// Round 14
// 136.810 us; speedup vs baseline: 1.1496x; 1.1496x over previous
//
#include <hip/hip_runtime.h>
#include <hip/hip_bf16.h>
#include <math.h>

#define TT 1024
#define HH 1024
#define NEXP 16
#define NI 704
#define SI 2048
#define UPMAX 506             // max active up tiles: 6*63 routed + 128 shared
#define WDTILES 1408          // wd transpose tiles (64r x 128c each) fused into k_up grid
#define DNSHARED 64           // shared down blocks (8 mt x 8 nt, K=2048)
#define DNMAX (DNSHARED + 504)

typedef unsigned short us;
typedef __attribute__((ext_vector_type(8))) __bf16 bf16x8;
typedef __attribute__((ext_vector_type(4))) float f32x4;
typedef __attribute__((ext_vector_type(4))) unsigned short us4;

__device__ __forceinline__ us f2bf(float f) {
  unsigned u = __builtin_bit_cast(unsigned, f);
  u += 0x7fffu + ((u >> 16) & 1u);   // RNE
  return (us)(u >> 16);
}

// Byte offset of 16B chunk (row, kg) in a [rows][32bf16] LDS tile,
// slot swizzle kg' = kg ^ ((row>>1)&3) (2-way residual = free, verified r12).
__device__ __forceinline__ int ldsOff(int row, int kg) {
  return (row * 4 + (kg ^ ((row >> 1) & 3))) * 16;
}

__device__ __forceinline__ void gl16(const void* g, void* l) {
  __builtin_amdgcn_global_load_lds((const __attribute__((address_space(1))) void*)g,
                                   (__attribute__((address_space(3))) void*)l, 16, 0, 0);
}

// m204 bijective XCD-chunk map: blocks with b%8==c process a contiguous
// item chunk -> same-weight tiles stay on one XCD's L2.
__device__ __forceinline__ int chunkMap(int b, int n) {
  int q = n >> 3, r = n & 7;
  int c = b & 7, i = b >> 3;
  int base = (c < r) ? c * (q + 1) : r * (q + 1) + (c - r) * q;
  return base + i;
}

// ---------------- 256-thread transpose+convert tile (64x64) ----------------
__device__ __forceinline__ void tconv_tile(const float* __restrict__ inz,
                                           us* __restrict__ outz,
                                           int C, int ldo, int r0, int c0,
                                           float (*tile)[65]) {
  int t = threadIdx.x;
  int rr = t >> 4, cc = (t & 15) * 4;
  #pragma unroll
  for (int i = 0; i < 4; ++i) {
    f32x4 v = *reinterpret_cast<const f32x4*>(inz + (size_t)(r0 + rr + i * 16) * C + c0 + cc);
    tile[rr + i*16][cc + 0] = v[0];
    tile[rr + i*16][cc + 1] = v[1];
    tile[rr + i*16][cc + 2] = v[2];
    tile[rr + i*16][cc + 3] = v[3];
  }
  __syncthreads();
  int c = t >> 2, rq = t & 3;
  us o0[8], o1[8];
  #pragma unroll
  for (int j = 0; j < 8; ++j) {
    o0[j] = f2bf(tile[rq * 16 + j][c]);
    o1[j] = f2bf(tile[rq * 16 + 8 + j][c]);
  }
  us* op = outz + (size_t)(c0 + c) * ldo + r0 + rq * 16;
  *reinterpret_cast<us4*>(op)      = *reinterpret_cast<us4*>(&o0[0]);
  *reinterpret_cast<us4*>(op + 4)  = *reinterpret_cast<us4*>(&o0[4]);
  *reinterpret_cast<us4*>(op + 8)  = *reinterpret_cast<us4*>(&o1[0]);
  *reinterpret_cast<us4*>(op + 12) = *reinterpret_cast<us4*>(&o1[4]);
}

// ---------------- 512-thread transpose+convert (64 rows x 128 cols) ----------------
// inz row stride HH; out[(h0+c)*NI + i0+r] = bf16(inz[(i0+r)*HH + h0+c])
__device__ __forceinline__ void tconv512(const float* __restrict__ inz,
                                         us* __restrict__ outz,
                                         int i0, int h0, float (*tile)[129]) {
  int t = threadIdx.x;
  int ir = t >> 3, cg = (t & 7) * 4;
  #pragma unroll
  for (int p = 0; p < 4; ++p) {
    f32x4 v = *reinterpret_cast<const f32x4*>(inz + (size_t)(i0 + ir) * HH + h0 + cg + p * 32);
    tile[ir][cg + p*32 + 0] = v[0];
    tile[ir][cg + p*32 + 1] = v[1];
    tile[ir][cg + p*32 + 2] = v[2];
    tile[ir][cg + p*32 + 3] = v[3];
  }
  __syncthreads();
  int c = t >> 2, rq = t & 3;
  us o[16];
  #pragma unroll
  for (int j = 0; j < 16; ++j) o[j] = f2bf(tile[rq * 16 + j][c]);
  us* op = outz + (size_t)(h0 + c) * NI + i0 + rq * 16;
  *reinterpret_cast<us4*>(op)      = *reinterpret_cast<us4*>(&o[0]);
  *reinterpret_cast<us4*>(op + 4)  = *reinterpret_cast<us4*>(&o[4]);
  *reinterpret_cast<us4*>(op + 8)  = *reinterpret_cast<us4*>(&o[8]);
  *reinterpret_cast<us4*>(op + 12) = *reinterpret_cast<us4*>(&o[12]);
}

// ---------------- prep: gate + h->bf16 + up-weight tconv, fused ----------------
__global__ __launch_bounds__(256) void k_prep(
    const float* __restrict__ h, const float* __restrict__ gw,
    const float* __restrict__ bias, float* __restrict__ cw,
    us* __restrict__ hb, unsigned* __restrict__ selpk,
    const float* __restrict__ wg, const float* __restrict__ wu,
    const float* __restrict__ swg, const float* __restrict__ swu,
    us* __restrict__ wgb, us* __restrict__ wub,
    us* __restrict__ swgb, us* __restrict__ swub) {
  __shared__ float tile[64][65];
  __shared__ float lgS[NEXP];
  int b = blockIdx.x;
  int tid = threadIdx.x;
  if (b < 1024) {
    int t = b;
    const float* hr = h + (size_t)t * HH;
    {
      f32x4 v = *reinterpret_cast<const f32x4*>(hr + tid * 4);
      us4 p;
      p[0] = f2bf(v[0]); p[1] = f2bf(v[1]); p[2] = f2bf(v[2]); p[3] = f2bf(v[3]);
      *reinterpret_cast<us4*>(hb + (size_t)t * HH + tid * 4) = p;
    }
    int e = tid >> 4, sub = tid & 15;
    const f32x4* hr4 = reinterpret_cast<const f32x4*>(hr);
    const f32x4* gr4 = reinterpret_cast<const f32x4*>(gw + (size_t)e * HH);
    float acc = 0.f;
    for (int i = sub; i < 256; i += 16) {
      f32x4 a = hr4[i], g = gr4[i];
      acc += a[0]*g[0] + a[1]*g[1] + a[2]*g[2] + a[3]*g[3];
    }
    acc += __shfl_down(acc, 8, 16);
    acc += __shfl_down(acc, 4, 16);
    acc += __shfl_down(acc, 2, 16);
    acc += __shfl_down(acc, 1, 16);
    if (sub == 0) lgS[e] = acc;
    __syncthreads();
    if (tid == 0) {
      float sc[NEXP], s4[NEXP];
      for (int i = 0; i < NEXP; ++i) {
        sc[i] = 1.f / (1.f + expf(-lgS[i]));
        s4[i] = sc[i] + bias[i];
      }
      float gs[4];
      for (int g = 0; g < 4; ++g) {
        float a = s4[4*g], bb = s4[4*g+1], c = s4[4*g+2], d = s4[4*g+3];
        float mx01 = fmaxf(a, bb), mn01 = fminf(a, bb);
        float mx23 = fmaxf(c, d), mn23 = fminf(c, d);
        float top = fmaxf(mx01, mx23);
        float sec = (mx01 >= mx23) ? fmaxf(mn01, mx23) : fmaxf(mn23, mx01);
        gs[g] = top + sec;
      }
      int g1 = 0;
      for (int g = 1; g < 4; ++g) if (gs[g] > gs[g1]) g1 = g;
      int g2 = -1;
      for (int g = 0; g < 4; ++g) { if (g == g1) continue; if (g2 < 0 || gs[g] > gs[g2]) g2 = g; }
      int sel[6];
      bool used[NEXP];
      for (int i = 0; i < NEXP; ++i) used[i] = false;
      float wsum = 0.f;
      for (int it = 0; it < 6; ++it) {
        int best = -1; float bv = 0.f;
        for (int i = 0; i < NEXP; ++i) {
          int grp = i >> 2;
          if ((grp != g1 && grp != g2) || used[i]) continue;
          if (best < 0 || s4[i] > bv) { best = i; bv = s4[i]; }
        }
        used[best] = true;
        sel[it] = best;
        wsum += sc[best];
      }
      float inv = 2.0f / wsum;   // ROUTED_SCALE folded
      unsigned pk = 0;
      for (int it = 0; it < 6; ++it) {
        pk |= (unsigned)sel[it] << (it * 4);
        cw[(size_t)t * NEXP + sel[it]] = sc[sel[it]] * inv;
      }
      selpk[t] = pk;
    }
    return;
  }
  b -= 1024;
  if (b < 2816) {        // wg: [16][1024 r][704 c] -> wgb [16][704][1024]
    int z = b / 176, r = b % 176;
    tconv_tile(wg + (size_t)z * HH * NI, wgb + (size_t)z * NI * HH,
               NI, HH, (r / 11) * 64, (r % 11) * 64, tile);
    return;
  }
  b -= 2816;
  if (b < 2816) {        // wu
    int z = b / 176, r = b % 176;
    tconv_tile(wu + (size_t)z * HH * NI, wub + (size_t)z * NI * HH,
               NI, HH, (r / 11) * 64, (r % 11) * 64, tile);
    return;
  }
  b -= 2816;
  if (b < 512) {         // swg
    tconv_tile(swg, swgb, SI, HH, (b >> 5) * 64, (b & 31) * 64, tile);
    return;
  }
  b -= 512;
  {                      // swu
    tconv_tile(swu, swub, SI, HH, (b >> 5) * 64, (b & 31) * 64, tile);
  }
}

// ------- deterministic list build + compact work lists (1 block, 16 waves) -------
__global__ void k_scan(const unsigned* __restrict__ selpk,
                       int* __restrict__ cnt, int* __restrict__ list,
                       int* __restrict__ wlUp, int* __restrict__ wlDn,
                       int* __restrict__ totals) {
  int t = threadIdx.x;           // token
  int w = t >> 6, l = t & 63;
  unsigned pk = selpk[t];
  unsigned short flags = 0;
  #pragma unroll
  for (int j = 0; j < 6; ++j) flags |= (unsigned short)(1u << ((pk >> (j * 4)) & 15));
  __shared__ int wc[16][16];
  __shared__ int pre[16][16];
  __shared__ int tiles_s[16], upo[16], dno[16], totR[2];
  #pragma unroll
  for (int e = 0; e < 16; ++e) {
    unsigned long long bal = __ballot((flags >> e) & 1);
    if (l == 0) wc[w][e] = __popcll(bal);
  }
  __syncthreads();
  if (t < 16) {                  // t = expert
    int s = 0;
    for (int ww = 0; ww < 16; ++ww) { pre[ww][t] = s; s += wc[ww][t]; }
    cnt[t] = s;
    tiles_s[t] = (s + 127) >> 7;
  }
  __syncthreads();
  if (t < 16) {
    int uo = 0, dn = 0;
    for (int e2 = 0; e2 < t; ++e2) { uo += 6 * tiles_s[e2]; dn += 8 * tiles_s[e2]; }
    upo[t] = uo; dno[t] = dn;
    if (t == 15) { totR[0] = uo + 6 * tiles_s[15]; totR[1] = dn + 8 * tiles_s[15]; }
  }
  __syncthreads();
  // routed items (wave w = expert w), nt-major (consecutive = same weights)
  {
    int te = tiles_s[w];
    for (int i = l; i < 6 * te; i += 64) {
      int nt = i / te, mt = i - nt * te;
      wlUp[upo[w] + i] = ((w * 6 + nt) << 3) | mt;
    }
    for (int i = l; i < 8 * te; i += 64) {
      int nt = i / te, mt = i - nt * te;
      wlDn[dno[w] + i] = ((w * 8 + nt) << 3) | mt;
    }
  }
  if (w == 0) {
    for (int j = l; j < 128; j += 64)              // shared up appended (16 nt x 8 mt)
      wlUp[totR[0] + j] = ((96 + (j >> 3)) << 3) | (j & 7);
  }
  if (t == 0) { totals[0] = totR[0] + 128; totals[1] = totR[1]; }
  unsigned long long lmask = (l == 0) ? 0ull : ((~0ull) >> (64 - l));
  #pragma unroll
  for (int e = 0; e < 16; ++e) {
    bool f = (flags >> e) & 1;
    unsigned long long bal = __ballot(f);
    if (f) {
      int rank = __popcll(bal & lmask);
      int j = 0;
      #pragma unroll
      for (int jj = 0; jj < 6; ++jj) j += (((pk >> (jj * 4)) & 15) == (unsigned)e) ? jj : 0;
      list[(e << 10) + pre[w][e] + rank] = (t << 3) | j;
    }
  }
}

// ---------------- swd transpose (aliases swgb, runs after k_upT) ----------------
__global__ void k_tconvS(const float* __restrict__ swd, us* __restrict__ swdT) {
  __shared__ float tile[64][65];
  int b = blockIdx.x;            // 512 blocks: [2048 r][1024 c] -> [1024][2048]
  tconv_tile(swd, swdT, HH, SI, (b >> 4) * 64, (b & 15) * 64, tile);
}

// ------- up: 128x128 dual-GEMM, 8 waves, 3-buffer counted-vmcnt + fused wd-tconv -------
__global__ __launch_bounds__(512) void k_upT(
    const us* __restrict__ hb,
    const us* __restrict__ wgb, const us* __restrict__ wub,
    const us* __restrict__ swgb, const us* __restrict__ swub,
    const float* __restrict__ cw, const int* __restrict__ list,
    const int* __restrict__ cnt, const int* __restrict__ wlUp,
    const int* __restrict__ totals,
    us* __restrict__ cact_r, us* __restrict__ cact_s,
    const float* __restrict__ wd, us* __restrict__ wdbT) {
  __shared__ __align__(16) char ldsb[73728];   // 3 x (A 8K | Bg 8K | Bu 8K)
  int tid = threadIdx.x;
  if ((int)blockIdx.x >= UPMAX) {
    // fused wd transpose: [16][704 r][1024 c] -> wdbT [16][1024][704]
    int b = blockIdx.x - UPMAX;
    int z = b / 88, r = b % 88;
    tconv512(wd + (size_t)z * NI * HH, wdbT + (size_t)z * HH * NI,
             (r >> 3) * 64, (r & 7) * 128,
             reinterpret_cast<float(*)[129]>(ldsb));
    return;
  }
  int tot = totals[0];
  if ((int)blockIdx.x >= tot) return;
  int item = wlUp[chunkMap(blockIdx.x, tot)];
  int group = item >> 3, mt = item & 7;
  int t0 = mt * 128;
  bool routed = group < 96;
  int e = 0, n0, cntE = TT;
  const us *bgBase, *buBase;
  if (routed) {
    e = group / 6;
    n0 = (group - e * 6) * 128;
    cntE = cnt[e];
    bgBase = wgb + (size_t)e * NI * HH;
    buBase = wub + (size_t)e * NI * HH;
  } else {
    n0 = (group - 96) * 128;
    bgBase = swgb;
    buBase = swub;
  }
  int w = tid >> 6, l = tid & 63;
  int wm = w >> 2, wn = w & 3;      // 2 (M) x 4 (N) wave grid
  int lr = l & 15, lg2 = l >> 4;

  int rowA = tid >> 2;              // 0..127 (1 chunk/thread per matrix)
  int kg = (tid & 3) ^ ((rowA >> 1) & 3);
  int tok = t0 + rowA;
  if (routed) tok = (tok < cntE) ? (list[(e << 10) + tok] >> 3) : 0;
  int bRow = n0 + rowA;
  if (routed && bRow >= NI) bRow = NI - 1;   // clamp edge N-tile (n0=640)
  const us* aS = hb + (size_t)tok * HH + kg * 8;
  const us* gS = bgBase + (size_t)bRow * HH + kg * 8;
  const us* uS = buBase + (size_t)bRow * HH + kg * 8;

  f32x4 accG[4][2] = {};
  f32x4 accU[4][2] = {};

  int wslot = w * 1024;
  auto stage = [&](char* buf) {     // 3 gl_lds per thread, then advance
    char* b = buf + wslot;          // wave-uniform dest + lane*16
    gl16(aS, b);
    gl16(gS, b + 8192);
    gl16(uS, b + 16384);
    aS += 32; gS += 32; uS += 32;
  };

  char* bA = ldsb;
  char* bB = ldsb + 24576;
  char* bC = ldsb + 49152;
  stage(bA);                        // k-step 0
  stage(bB);                        // k-step 1
  for (int ki = 0; ki < 32; ++ki) {
    if (ki < 30) {
      stage(bC);                                            // depth-2 prefetch
      asm volatile("s_waitcnt vmcnt(6)" ::: "memory");      // stage(ki) landed
    } else if (ki == 30) {
      asm volatile("s_waitcnt vmcnt(3)" ::: "memory");
    } else {
      asm volatile("s_waitcnt vmcnt(0)" ::: "memory");
    }
    __builtin_amdgcn_s_barrier();
    asm volatile("" ::: "memory");
    bf16x8 af[4], bg[2], bu[2];
    #pragma unroll
    for (int rf = 0; rf < 4; ++rf)
      af[rf] = *reinterpret_cast<const bf16x8*>(bA + ldsOff(wm * 64 + rf * 16 + lr, lg2));
    #pragma unroll
    for (int cf = 0; cf < 2; ++cf) {
      int n = wn * 32 + cf * 16 + lr;
      bg[cf] = *reinterpret_cast<const bf16x8*>(bA + 8192  + ldsOff(n, lg2));
      bu[cf] = *reinterpret_cast<const bf16x8*>(bA + 16384 + ldsOff(n, lg2));
    }
    __builtin_amdgcn_s_setprio(1);
    #pragma unroll
    for (int rf = 0; rf < 4; ++rf)
      #pragma unroll
      for (int cf = 0; cf < 2; ++cf) {
        accG[rf][cf] = __builtin_amdgcn_mfma_f32_16x16x32_bf16(af[rf], bg[cf], accG[rf][cf], 0, 0, 0);
        accU[rf][cf] = __builtin_amdgcn_mfma_f32_16x16x32_bf16(af[rf], bu[cf], accU[rf][cf], 0, 0, 0);
      }
    __builtin_amdgcn_s_setprio(0);
    __builtin_amdgcn_s_barrier();
    asm volatile("" ::: "memory");
    char* tp = bA; bA = bB; bB = bC; bC = tp;               // rotate (no indexing)
  }
  #pragma unroll
  for (int rf = 0; rf < 4; ++rf)
    #pragma unroll
    for (int cf = 0; cf < 2; ++cf)
      #pragma unroll
      for (int r = 0; r < 4; ++r) {
        int row = wm * 64 + rf * 16 + lg2 * 4 + r;
        int col = wn * 32 + cf * 16 + lr;
        float g = accG[rf][cf][r], u = accU[rf][cf][r];
        float act = g / (1.f + __expf(-g)) * u;
        if (routed) {
          int slot = t0 + row;
          if (slot < cntE && n0 + col < NI) {
            int packed = list[(e << 10) + slot];
            float scl = cw[(size_t)(packed >> 3) * NEXP + e];
            cact_r[((size_t)(e << 10) + slot) * NI + n0 + col] = f2bf(act * scl);
          }
        } else {
          cact_s[(size_t)(t0 + row) * SI + n0 + col] = f2bf(act);
        }
      }
}

// ------- down: [0,64) shared K=2048 -> out direct; rest routed -> bf16 part[t][j] -------
__global__ __launch_bounds__(256) void k_down(
    const us* __restrict__ cact_r, const us* __restrict__ cact_s,
    const us* __restrict__ wdbT, const us* __restrict__ swdT,
    const int* __restrict__ list, const int* __restrict__ cnt,
    const int* __restrict__ wlDn, const int* __restrict__ totals,
    us* __restrict__ part, float* __restrict__ out) {
  __shared__ __align__(16) char ldsb[32768];
  int tid = threadIdx.x;
  int b = blockIdx.x;
  bool routed;
  int e = 0, nt, mt, kiter, Ksrc, cntE = TT;
  const us *Ab, *Bb;
  if (b < DNSHARED) {
    routed = false;
    nt = b & 7;
    mt = b >> 3;
    kiter = 64;                 // full K=2048
    Ksrc = SI;
    Ab = cact_s;
    Bb = swdT;
  } else {
    routed = true;
    int rb = b - DNSHARED;
    int tot = totals[1];
    if (rb >= tot) return;
    int item = wlDn[chunkMap(rb, tot)];
    int group = item >> 3;
    mt = item & 7;
    e = group >> 3; nt = group & 7;
    cntE = cnt[e];
    kiter = NI / 32;            // 22
    Ksrc = NI;
    Ab = cact_r + (size_t)e * 1024 * NI;
    Bb = wdbT + (size_t)e * 1024 * NI;
  }
  int t0 = mt * 128;
  int n0 = nt * 128;
  int w = tid >> 6, l = tid & 63;
  int wm = w >> 1, wn = w & 1;
  int lr = l & 15, lg2 = l >> 4;

  int rowA = tid >> 2;
  int kg = (tid & 3) ^ ((rowA >> 1) & 3);
  const us* aS0 = Ab + (size_t)(t0 + rowA) * Ksrc + kg * 8;
  const us* aS1 = Ab + (size_t)(t0 + 64 + rowA) * Ksrc + kg * 8;
  const us* bS0 = Bb + (size_t)(n0 + rowA) * Ksrc + kg * 8;
  const us* bS1 = Bb + (size_t)(n0 + 64 + rowA) * Ksrc + kg * 8;

  f32x4 acc[4][4] = {};

  int wslot = w * 1024;
  auto stage = [&](char* buf) {
    char* bp = buf + wslot;
    gl16(aS0, bp);
    gl16(aS1, bp + 4096);
    gl16(bS0, bp + 8192);
    gl16(bS1, bp + 12288);
    aS0 += 32; aS1 += 32; bS0 += 32; bS1 += 32;
  };

  char* bufR = ldsb;
  char* bufW = ldsb + 16384;
  stage(bufR);
  __syncthreads();
  for (int ki = 0; ki < kiter; ++ki) {
    if (ki + 1 < kiter) stage(bufW);
    bf16x8 af[4], bb[4];
    #pragma unroll
    for (int rf = 0; rf < 4; ++rf)
      af[rf] = *reinterpret_cast<const bf16x8*>(bufR + ldsOff(wm * 64 + rf * 16 + lr, lg2));
    #pragma unroll
    for (int cf = 0; cf < 4; ++cf)
      bb[cf] = *reinterpret_cast<const bf16x8*>(bufR + 8192 + ldsOff(wn * 64 + cf * 16 + lr, lg2));
    #pragma unroll
    for (int rf = 0; rf < 4; ++rf)
      #pragma unroll
      for (int cf = 0; cf < 4; ++cf)
        acc[rf][cf] = __builtin_amdgcn_mfma_f32_16x16x32_bf16(af[rf], bb[cf], acc[rf][cf], 0, 0, 0);
    __syncthreads();
    char* tp = bufR; bufR = bufW; bufW = tp;
  }
  #pragma unroll
  for (int rf = 0; rf < 4; ++rf)
    #pragma unroll
    for (int cf = 0; cf < 4; ++cf)
      #pragma unroll
      for (int r = 0; r < 4; ++r) {
        int row = wm * 64 + rf * 16 + lg2 * 4 + r;
        int col = wn * 64 + cf * 16 + lr;
        if (routed) {
          int slot = t0 + row;
          if (slot < cntE) {
            int packed = list[(e << 10) + slot];
            int t = packed >> 3, j = packed & 7;
            part[((size_t)t * 6 + j) * 1024 + n0 + col] = f2bf(acc[rf][cf][r]);
          }
        } else {
          out[(size_t)(t0 + row) * HH + n0 + col] = acc[rf][cf][r];
        }
      }
}

__global__ void k_reduce(const us* __restrict__ part, float* __restrict__ out) {
  int i = (blockIdx.x * blockDim.x + threadIdx.x) * 4;
  int t = i >> 10, hh = i & 1023;
  f32x4 s = *reinterpret_cast<const f32x4*>(out + i);   // shared-expert result
  #pragma unroll
  for (int j = 0; j < 6; ++j) {
    us4 p = *reinterpret_cast<const us4*>(part + ((size_t)t * 6 + j) * 1024 + hh);
    #pragma unroll
    for (int k = 0; k < 4; ++k)
      s[k] += __builtin_bit_cast(float, (unsigned)p[k] << 16);
  }
  *reinterpret_cast<f32x4*>(out + i) = s;
}

// ---- workspace layout (total ~102.2 MiB) ----
#define HB_OFF    0ULL
#define CW_OFF    2097152ULL
#define CNT_OFF   2162688ULL
#define SELPK_OFF 2166784ULL
#define LIST_OFF  2170880ULL
#define WLUP_OFF  2236416ULL
#define WLDN_OFF  2244608ULL
#define TOT_OFF   2252800ULL
#define CACTR_OFF 2260992ULL           // 23.07 MB [16*1024][704] bf16
#define CACTS_OFF 25329664ULL          // 4 MB [1024][2048] bf16
#define WGB_OFF   29523968ULL          // 23.07 MB (dead after k_upT)
#define WUB_OFF   52592640ULL          // 23.07 MB (dead after k_upT)
#define SWGB_OFF  75661312ULL          // 4 MB (dead after k_upT)
#define SWUB_OFF  79855616ULL          // 4 MB (dead after k_upT)
#define WDBT_OFF  84049920ULL          // 22.53 MB disjoint (written DURING k_upT)
#define SWDT_OFF  SWGB_OFF             // alias swgb: written by k_tconvS after k_upT
#define PART_OFF  WGB_OFF              // alias wgb: 12 MB [1024][6][1024] bf16

extern "C" void kernel_launch(void* const* d_in, const int* in_sizes, int n_in,
                              void* d_out, int out_size, void* d_ws, size_t ws_size,
                              hipStream_t stream) {
  const float* h    = (const float*)d_in[0];
  const float* gw   = (const float*)d_in[1];
  const float* bias = (const float*)d_in[2];
  const float* wg   = (const float*)d_in[3];
  const float* wu   = (const float*)d_in[4];
  const float* wd   = (const float*)d_in[5];
  const float* swg  = (const float*)d_in[6];
  const float* swu  = (const float*)d_in[7];
  const float* swd  = (const float*)d_in[8];
  float* out = (float*)d_out;

  char* ws = (char*)d_ws;
  us*       hb     = (us*)(ws + HB_OFF);
  float*    cw     = (float*)(ws + CW_OFF);
  int*      cnt    = (int*)(ws + CNT_OFF);
  unsigned* selpk  = (unsigned*)(ws + SELPK_OFF);
  int*      list   = (int*)(ws + LIST_OFF);
  int*      wlUp   = (int*)(ws + WLUP_OFF);
  int*      wlDn   = (int*)(ws + WLDN_OFF);
  int*      totals = (int*)(ws + TOT_OFF);
  us*       cact_r = (us*)(ws + CACTR_OFF);
  us*       cact_s = (us*)(ws + CACTS_OFF);
  us*       wgb    = (us*)(ws + WGB_OFF);
  us*       wub    = (us*)(ws + WUB_OFF);
  us*       swgb   = (us*)(ws + SWGB_OFF);
  us*       swub   = (us*)(ws + SWUB_OFF);
  us*       wdbT   = (us*)(ws + WDBT_OFF);
  us*       swdT   = (us*)(ws + SWDT_OFF);
  us*       part   = (us*)(ws + PART_OFF);

  k_prep<<<7680, 256, 0, stream>>>(h, gw, bias, cw, hb, selpk,
                                   wg, wu, swg, swu, wgb, wub, swgb, swub);
  k_scan<<<1, 1024, 0, stream>>>(selpk, cnt, list, wlUp, wlDn, totals);

  // up-GEMM (128x128 dual, 512 thr) with wd-transpose blocks fused
  k_upT<<<UPMAX + WDTILES, 512, 0, stream>>>(hb, wgb, wub, swgb, swub, cw, list,
                                             cnt, wlUp, totals, cact_r, cact_s,
                                             wd, wdbT);

  k_tconvS<<<512, 256, 0, stream>>>(swd, swdT);   // swdT aliases swgb (now dead)

  k_down<<<DNMAX, 256, 0, stream>>>(cact_r, cact_s, wdbT, swdT, list, cnt,
                                    wlDn, totals, part, out);
  k_reduce<<<1024, 256, 0, stream>>>(part, out);
}

// Round 15
// 131.440 us; speedup vs baseline: 1.1966x; 1.0409x over previous
//
#include <hip/hip_runtime.h>
#include <hip/hip_bf16.h>
#include <math.h>

#define TT 1024
#define HH 1024
#define NEXP 16
#define NI 704
#define SI 2048
#define UPMAX 506             // max active up tiles: 6*63 routed + 128 shared
#define WDTILES 1408          // wd transpose tiles (64r x 128c each) fused into k_up grid
#define DNSHARED 64           // shared down blocks (8 mt x 8 nt, K=2048)
#define DNMAX (DNSHARED + 504)

typedef unsigned short us;
typedef __attribute__((ext_vector_type(8))) __bf16 bf16x8;
typedef __attribute__((ext_vector_type(4))) float f32x4;
typedef __attribute__((ext_vector_type(4))) unsigned short us4;

__device__ __forceinline__ us f2bf(float f) {
  unsigned u = __builtin_bit_cast(unsigned, f);
  u += 0x7fffu + ((u >> 16) & 1u);   // RNE
  return (us)(u >> 16);
}

// Byte offset of 16B chunk (row, kg) in a [rows][32bf16] LDS tile,
// slot swizzle kg' = kg ^ ((row>>1)&3) (2-way residual = free, verified r12).
__device__ __forceinline__ int ldsOff(int row, int kg) {
  return (row * 4 + (kg ^ ((row >> 1) & 3))) * 16;
}

__device__ __forceinline__ void gl16(const void* g, void* l) {
  __builtin_amdgcn_global_load_lds((const __attribute__((address_space(1))) void*)g,
                                   (__attribute__((address_space(3))) void*)l, 16, 0, 0);
}

// m204 bijective XCD-chunk map: blocks with b%8==c process a contiguous
// item chunk -> same-weight tiles stay on one XCD's L2.
__device__ __forceinline__ int chunkMap(int b, int n) {
  int q = n >> 3, r = n & 7;
  int c = b & 7, i = b >> 3;
  int base = (c < r) ? c * (q + 1) : r * (q + 1) + (c - r) * q;
  return base + i;
}

// ---------------- 256-thread transpose+convert tile (64x64) ----------------
__device__ __forceinline__ void tconv_tile(const float* __restrict__ inz,
                                           us* __restrict__ outz,
                                           int C, int ldo, int r0, int c0,
                                           float (*tile)[65]) {
  int t = threadIdx.x;
  int rr = t >> 4, cc = (t & 15) * 4;
  #pragma unroll
  for (int i = 0; i < 4; ++i) {
    f32x4 v = *reinterpret_cast<const f32x4*>(inz + (size_t)(r0 + rr + i * 16) * C + c0 + cc);
    tile[rr + i*16][cc + 0] = v[0];
    tile[rr + i*16][cc + 1] = v[1];
    tile[rr + i*16][cc + 2] = v[2];
    tile[rr + i*16][cc + 3] = v[3];
  }
  __syncthreads();
  int c = t >> 2, rq = t & 3;
  us o0[8], o1[8];
  #pragma unroll
  for (int j = 0; j < 8; ++j) {
    o0[j] = f2bf(tile[rq * 16 + j][c]);
    o1[j] = f2bf(tile[rq * 16 + 8 + j][c]);
  }
  us* op = outz + (size_t)(c0 + c) * ldo + r0 + rq * 16;
  *reinterpret_cast<us4*>(op)      = *reinterpret_cast<us4*>(&o0[0]);
  *reinterpret_cast<us4*>(op + 4)  = *reinterpret_cast<us4*>(&o0[4]);
  *reinterpret_cast<us4*>(op + 8)  = *reinterpret_cast<us4*>(&o1[0]);
  *reinterpret_cast<us4*>(op + 12) = *reinterpret_cast<us4*>(&o1[4]);
}

// ---------------- 512-thread transpose+convert (64 rows x 128 cols) ----------------
// inz row stride HH; out[(h0+c)*NI + i0+r] = bf16(inz[(i0+r)*HH + h0+c])
__device__ __forceinline__ void tconv512(const float* __restrict__ inz,
                                         us* __restrict__ outz,
                                         int i0, int h0, float (*tile)[129]) {
  int t = threadIdx.x;
  int ir = t >> 3, cg = (t & 7) * 4;
  #pragma unroll
  for (int p = 0; p < 4; ++p) {
    f32x4 v = *reinterpret_cast<const f32x4*>(inz + (size_t)(i0 + ir) * HH + h0 + cg + p * 32);
    tile[ir][cg + p*32 + 0] = v[0];
    tile[ir][cg + p*32 + 1] = v[1];
    tile[ir][cg + p*32 + 2] = v[2];
    tile[ir][cg + p*32 + 3] = v[3];
  }
  __syncthreads();
  int c = t >> 2, rq = t & 3;
  us o[16];
  #pragma unroll
  for (int j = 0; j < 16; ++j) o[j] = f2bf(tile[rq * 16 + j][c]);
  us* op = outz + (size_t)(h0 + c) * NI + i0 + rq * 16;
  *reinterpret_cast<us4*>(op)      = *reinterpret_cast<us4*>(&o[0]);
  *reinterpret_cast<us4*>(op + 4)  = *reinterpret_cast<us4*>(&o[4]);
  *reinterpret_cast<us4*>(op + 8)  = *reinterpret_cast<us4*>(&o[8]);
  *reinterpret_cast<us4*>(op + 12) = *reinterpret_cast<us4*>(&o[12]);
}

// ---------------- prep: gate + h->bf16 + up-weight tconv, fused ----------------
__global__ __launch_bounds__(256) void k_prep(
    const float* __restrict__ h, const float* __restrict__ gw,
    const float* __restrict__ bias, float* __restrict__ cw,
    us* __restrict__ hb, unsigned* __restrict__ selpk,
    const float* __restrict__ wg, const float* __restrict__ wu,
    const float* __restrict__ swg, const float* __restrict__ swu,
    us* __restrict__ wgb, us* __restrict__ wub,
    us* __restrict__ swgb, us* __restrict__ swub) {
  __shared__ float tile[64][65];
  __shared__ float lgS[NEXP];
  int b = blockIdx.x;
  int tid = threadIdx.x;
  if (b < 1024) {
    int t = b;
    const float* hr = h + (size_t)t * HH;
    {
      f32x4 v = *reinterpret_cast<const f32x4*>(hr + tid * 4);
      us4 p;
      p[0] = f2bf(v[0]); p[1] = f2bf(v[1]); p[2] = f2bf(v[2]); p[3] = f2bf(v[3]);
      *reinterpret_cast<us4*>(hb + (size_t)t * HH + tid * 4) = p;
    }
    int e = tid >> 4, sub = tid & 15;
    const f32x4* hr4 = reinterpret_cast<const f32x4*>(hr);
    const f32x4* gr4 = reinterpret_cast<const f32x4*>(gw + (size_t)e * HH);
    float acc = 0.f;
    for (int i = sub; i < 256; i += 16) {
      f32x4 a = hr4[i], g = gr4[i];
      acc += a[0]*g[0] + a[1]*g[1] + a[2]*g[2] + a[3]*g[3];
    }
    acc += __shfl_down(acc, 8, 16);
    acc += __shfl_down(acc, 4, 16);
    acc += __shfl_down(acc, 2, 16);
    acc += __shfl_down(acc, 1, 16);
    if (sub == 0) lgS[e] = acc;
    __syncthreads();
    if (tid == 0) {
      float sc[NEXP], s4[NEXP];
      for (int i = 0; i < NEXP; ++i) {
        sc[i] = 1.f / (1.f + expf(-lgS[i]));
        s4[i] = sc[i] + bias[i];
      }
      float gs[4];
      for (int g = 0; g < 4; ++g) {
        float a = s4[4*g], bb = s4[4*g+1], c = s4[4*g+2], d = s4[4*g+3];
        float mx01 = fmaxf(a, bb), mn01 = fminf(a, bb);
        float mx23 = fmaxf(c, d), mn23 = fminf(c, d);
        float top = fmaxf(mx01, mx23);
        float sec = (mx01 >= mx23) ? fmaxf(mn01, mx23) : fmaxf(mn23, mx01);
        gs[g] = top + sec;
      }
      int g1 = 0;
      for (int g = 1; g < 4; ++g) if (gs[g] > gs[g1]) g1 = g;
      int g2 = -1;
      for (int g = 0; g < 4; ++g) { if (g == g1) continue; if (g2 < 0 || gs[g] > gs[g2]) g2 = g; }
      int sel[6];
      bool used[NEXP];
      for (int i = 0; i < NEXP; ++i) used[i] = false;
      float wsum = 0.f;
      for (int it = 0; it < 6; ++it) {
        int best = -1; float bv = 0.f;
        for (int i = 0; i < NEXP; ++i) {
          int grp = i >> 2;
          if ((grp != g1 && grp != g2) || used[i]) continue;
          if (best < 0 || s4[i] > bv) { best = i; bv = s4[i]; }
        }
        used[best] = true;
        sel[it] = best;
        wsum += sc[best];
      }
      float inv = 2.0f / wsum;   // ROUTED_SCALE folded
      unsigned pk = 0;
      for (int it = 0; it < 6; ++it) {
        pk |= (unsigned)sel[it] << (it * 4);
        cw[(size_t)t * NEXP + sel[it]] = sc[sel[it]] * inv;
      }
      selpk[t] = pk;
    }
    return;
  }
  b -= 1024;
  if (b < 2816) {        // wg: [16][1024 r][704 c] -> wgb [16][704][1024]
    int z = b / 176, r = b % 176;
    tconv_tile(wg + (size_t)z * HH * NI, wgb + (size_t)z * NI * HH,
               NI, HH, (r / 11) * 64, (r % 11) * 64, tile);
    return;
  }
  b -= 2816;
  if (b < 2816) {        // wu
    int z = b / 176, r = b % 176;
    tconv_tile(wu + (size_t)z * HH * NI, wub + (size_t)z * NI * HH,
               NI, HH, (r / 11) * 64, (r % 11) * 64, tile);
    return;
  }
  b -= 2816;
  if (b < 512) {         // swg
    tconv_tile(swg, swgb, SI, HH, (b >> 5) * 64, (b & 31) * 64, tile);
    return;
  }
  b -= 512;
  {                      // swu
    tconv_tile(swu, swub, SI, HH, (b >> 5) * 64, (b & 31) * 64, tile);
  }
}

// ------- deterministic list build + compact work lists (1 block, 16 waves) -------
__global__ void k_scan(const unsigned* __restrict__ selpk,
                       int* __restrict__ cnt, int* __restrict__ list,
                       int* __restrict__ wlUp, int* __restrict__ wlDn,
                       int* __restrict__ totals) {
  int t = threadIdx.x;           // token
  int w = t >> 6, l = t & 63;
  unsigned pk = selpk[t];
  unsigned short flags = 0;
  #pragma unroll
  for (int j = 0; j < 6; ++j) flags |= (unsigned short)(1u << ((pk >> (j * 4)) & 15));
  __shared__ int wc[16][16];
  __shared__ int pre[16][16];
  __shared__ int tiles_s[16], upo[16], dno[16], totR[2];
  #pragma unroll
  for (int e = 0; e < 16; ++e) {
    unsigned long long bal = __ballot((flags >> e) & 1);
    if (l == 0) wc[w][e] = __popcll(bal);
  }
  __syncthreads();
  if (t < 16) {                  // t = expert
    int s = 0;
    for (int ww = 0; ww < 16; ++ww) { pre[ww][t] = s; s += wc[ww][t]; }
    cnt[t] = s;
    tiles_s[t] = (s + 127) >> 7;
  }
  __syncthreads();
  if (t < 16) {
    int uo = 0, dn = 0;
    for (int e2 = 0; e2 < t; ++e2) { uo += 6 * tiles_s[e2]; dn += 8 * tiles_s[e2]; }
    upo[t] = uo; dno[t] = dn;
    if (t == 15) { totR[0] = uo + 6 * tiles_s[15]; totR[1] = dn + 8 * tiles_s[15]; }
  }
  __syncthreads();
  // routed items (wave w = expert w), nt-major (consecutive = same weights)
  {
    int te = tiles_s[w];
    for (int i = l; i < 6 * te; i += 64) {
      int nt = i / te, mt = i - nt * te;
      wlUp[upo[w] + i] = ((w * 6 + nt) << 3) | mt;
    }
    for (int i = l; i < 8 * te; i += 64) {
      int nt = i / te, mt = i - nt * te;
      wlDn[dno[w] + i] = ((w * 8 + nt) << 3) | mt;
    }
  }
  if (w == 0) {
    for (int j = l; j < 128; j += 64)              // shared up appended (16 nt x 8 mt)
      wlUp[totR[0] + j] = ((96 + (j >> 3)) << 3) | (j & 7);
  }
  if (t == 0) { totals[0] = totR[0] + 128; totals[1] = totR[1]; }
  unsigned long long lmask = (l == 0) ? 0ull : ((~0ull) >> (64 - l));
  #pragma unroll
  for (int e = 0; e < 16; ++e) {
    bool f = (flags >> e) & 1;
    unsigned long long bal = __ballot(f);
    if (f) {
      int rank = __popcll(bal & lmask);
      int j = 0;
      #pragma unroll
      for (int jj = 0; jj < 6; ++jj) j += (((pk >> (jj * 4)) & 15) == (unsigned)e) ? jj : 0;
      list[(e << 10) + pre[w][e] + rank] = (t << 3) | j;
    }
  }
}

// ---------------- swd transpose (aliases swgb, runs after k_upT) ----------------
__global__ void k_tconvS(const float* __restrict__ swd, us* __restrict__ swdT) {
  __shared__ float tile[64][65];
  int b = blockIdx.x;            // 512 blocks: [2048 r][1024 c] -> [1024][2048]
  tconv_tile(swd, swdT, HH, SI, (b >> 4) * 64, (b & 15) * 64, tile);
}

// ------- up: 128x128 dual-GEMM, 8 waves, 3-buffer counted-vmcnt + fused wd-tconv -------
__global__ __launch_bounds__(512) void k_upT(
    const us* __restrict__ hb,
    const us* __restrict__ wgb, const us* __restrict__ wub,
    const us* __restrict__ swgb, const us* __restrict__ swub,
    const float* __restrict__ cw, const int* __restrict__ list,
    const int* __restrict__ cnt, const int* __restrict__ wlUp,
    const int* __restrict__ totals,
    us* __restrict__ cact_r, us* __restrict__ cact_s,
    const float* __restrict__ wd, us* __restrict__ wdbT) {
  __shared__ __align__(16) char ldsb[73728];   // 3 x (A 8K | Bg 8K | Bu 8K)
  int tid = threadIdx.x;
  if ((int)blockIdx.x >= UPMAX) {
    // fused wd transpose: [16][704 r][1024 c] -> wdbT [16][1024][704]
    int b = blockIdx.x - UPMAX;
    int z = b / 88, r = b % 88;
    tconv512(wd + (size_t)z * NI * HH, wdbT + (size_t)z * HH * NI,
             (r >> 3) * 64, (r & 7) * 128,
             reinterpret_cast<float(*)[129]>(ldsb));
    return;
  }
  int tot = totals[0];
  if ((int)blockIdx.x >= tot) return;
  int item = wlUp[chunkMap(blockIdx.x, tot)];
  int group = item >> 3, mt = item & 7;
  int t0 = mt * 128;
  bool routed = group < 96;
  int e = 0, n0, cntE = TT;
  const us *bgBase, *buBase;
  if (routed) {
    e = group / 6;
    n0 = (group - e * 6) * 128;
    cntE = cnt[e];
    bgBase = wgb + (size_t)e * NI * HH;
    buBase = wub + (size_t)e * NI * HH;
  } else {
    n0 = (group - 96) * 128;
    bgBase = swgb;
    buBase = swub;
  }
  int w = tid >> 6, l = tid & 63;
  int wm = w >> 2, wn = w & 3;      // 2 (M) x 4 (N) wave grid
  int lr = l & 15, lg2 = l >> 4;

  int rowA = tid >> 2;              // 0..127 (1 chunk/thread per matrix)
  int kg = (tid & 3) ^ ((rowA >> 1) & 3);
  int tok = t0 + rowA;
  if (routed) tok = (tok < cntE) ? (list[(e << 10) + tok] >> 3) : 0;
  int bRow = n0 + rowA;
  if (routed && bRow >= NI) bRow = NI - 1;   // clamp edge N-tile (n0=640)
  const us* aS = hb + (size_t)tok * HH + kg * 8;
  const us* gS = bgBase + (size_t)bRow * HH + kg * 8;
  const us* uS = buBase + (size_t)bRow * HH + kg * 8;

  f32x4 accG[4][2] = {};
  f32x4 accU[4][2] = {};

  int wslot = w * 1024;
  auto stage = [&](char* buf) {     // 3 gl_lds per thread, then advance
    char* b = buf + wslot;          // wave-uniform dest + lane*16
    gl16(aS, b);
    gl16(gS, b + 8192);
    gl16(uS, b + 16384);
    aS += 32; gS += 32; uS += 32;
  };

  char* bA = ldsb;
  char* bB = ldsb + 24576;
  char* bC = ldsb + 49152;
  stage(bA);                        // k-step 0
  stage(bB);                        // k-step 1
  for (int ki = 0; ki < 32; ++ki) {
    if (ki < 30) {
      stage(bC);                                            // depth-2 prefetch
      asm volatile("s_waitcnt vmcnt(6)" ::: "memory");      // stage(ki) landed
    } else if (ki == 30) {
      asm volatile("s_waitcnt vmcnt(3)" ::: "memory");
    } else {
      asm volatile("s_waitcnt vmcnt(0)" ::: "memory");
    }
    __builtin_amdgcn_s_barrier();
    asm volatile("" ::: "memory");
    bf16x8 af[4], bg[2], bu[2];
    #pragma unroll
    for (int rf = 0; rf < 4; ++rf)
      af[rf] = *reinterpret_cast<const bf16x8*>(bA + ldsOff(wm * 64 + rf * 16 + lr, lg2));
    #pragma unroll
    for (int cf = 0; cf < 2; ++cf) {
      int n = wn * 32 + cf * 16 + lr;
      bg[cf] = *reinterpret_cast<const bf16x8*>(bA + 8192  + ldsOff(n, lg2));
      bu[cf] = *reinterpret_cast<const bf16x8*>(bA + 16384 + ldsOff(n, lg2));
    }
    __builtin_amdgcn_s_setprio(1);
    #pragma unroll
    for (int rf = 0; rf < 4; ++rf)
      #pragma unroll
      for (int cf = 0; cf < 2; ++cf) {
        accG[rf][cf] = __builtin_amdgcn_mfma_f32_16x16x32_bf16(af[rf], bg[cf], accG[rf][cf], 0, 0, 0);
        accU[rf][cf] = __builtin_amdgcn_mfma_f32_16x16x32_bf16(af[rf], bu[cf], accU[rf][cf], 0, 0, 0);
      }
    __builtin_amdgcn_s_setprio(0);
    __builtin_amdgcn_s_barrier();
    asm volatile("" ::: "memory");
    char* tp = bA; bA = bB; bB = bC; bC = tp;               // rotate (no indexing)
  }
  #pragma unroll
  for (int rf = 0; rf < 4; ++rf)
    #pragma unroll
    for (int cf = 0; cf < 2; ++cf)
      #pragma unroll
      for (int r = 0; r < 4; ++r) {
        int row = wm * 64 + rf * 16 + lg2 * 4 + r;
        int col = wn * 32 + cf * 16 + lr;
        float g = accG[rf][cf][r], u = accU[rf][cf][r];
        float act = g / (1.f + __expf(-g)) * u;
        if (routed) {
          int slot = t0 + row;
          if (slot < cntE && n0 + col < NI) {
            int packed = list[(e << 10) + slot];
            float scl = cw[(size_t)(packed >> 3) * NEXP + e];
            cact_r[((size_t)(e << 10) + slot) * NI + n0 + col] = f2bf(act * scl);
          }
        } else {
          cact_s[(size_t)(t0 + row) * SI + n0 + col] = f2bf(act);
        }
      }
}

// ------- down: 3-buffer counted-vmcnt; [0,64) shared K=2048 -> out; rest routed -> bf16 part -------
__global__ __launch_bounds__(256) void k_down(
    const us* __restrict__ cact_r, const us* __restrict__ cact_s,
    const us* __restrict__ wdbT, const us* __restrict__ swdT,
    const int* __restrict__ list, const int* __restrict__ cnt,
    const int* __restrict__ wlDn, const int* __restrict__ totals,
    us* __restrict__ part, float* __restrict__ out) {
  __shared__ __align__(16) char ldsb[49152];   // 3 x (A 8K | B 8K)
  int tid = threadIdx.x;
  int b = blockIdx.x;
  bool routed;
  int e = 0, nt, mt, kiter, Ksrc, cntE = TT;
  const us *Ab, *Bb;
  if (b < DNSHARED) {
    routed = false;
    nt = b & 7;
    mt = b >> 3;
    kiter = 64;                 // full K=2048
    Ksrc = SI;
    Ab = cact_s;
    Bb = swdT;
  } else {
    routed = true;
    int rb = b - DNSHARED;
    int tot = totals[1];
    if (rb >= tot) return;
    int item = wlDn[chunkMap(rb, tot)];
    int group = item >> 3;
    mt = item & 7;
    e = group >> 3; nt = group & 7;
    cntE = cnt[e];
    kiter = NI / 32;            // 22
    Ksrc = NI;
    Ab = cact_r + (size_t)e * 1024 * NI;
    Bb = wdbT + (size_t)e * 1024 * NI;
  }
  int t0 = mt * 128;
  int n0 = nt * 128;
  int w = tid >> 6, l = tid & 63;
  int wm = w >> 1, wn = w & 1;
  int lr = l & 15, lg2 = l >> 4;

  int rowA = tid >> 2;
  int kg = (tid & 3) ^ ((rowA >> 1) & 3);
  const us* aS0 = Ab + (size_t)(t0 + rowA) * Ksrc + kg * 8;
  const us* aS1 = Ab + (size_t)(t0 + 64 + rowA) * Ksrc + kg * 8;
  const us* bS0 = Bb + (size_t)(n0 + rowA) * Ksrc + kg * 8;
  const us* bS1 = Bb + (size_t)(n0 + 64 + rowA) * Ksrc + kg * 8;

  f32x4 acc[4][4] = {};

  int wslot = w * 1024;
  auto stage = [&](char* buf) {
    char* bp = buf + wslot;
    gl16(aS0, bp);
    gl16(aS1, bp + 4096);
    gl16(bS0, bp + 8192);
    gl16(bS1, bp + 12288);
    aS0 += 32; aS1 += 32; bS0 += 32; bS1 += 32;
  };

  char* bA = ldsb;
  char* bB = ldsb + 16384;
  char* bC = ldsb + 32768;
  stage(bA);
  stage(bB);
  for (int ki = 0; ki < kiter; ++ki) {
    if (ki + 2 < kiter) {
      stage(bC);                                            // depth-2 prefetch
      asm volatile("s_waitcnt vmcnt(8)" ::: "memory");      // stage(ki) landed
    } else if (ki + 2 == kiter) {
      asm volatile("s_waitcnt vmcnt(4)" ::: "memory");
    } else {
      asm volatile("s_waitcnt vmcnt(0)" ::: "memory");
    }
    __builtin_amdgcn_s_barrier();
    asm volatile("" ::: "memory");
    bf16x8 af[4], bb[4];
    #pragma unroll
    for (int rf = 0; rf < 4; ++rf)
      af[rf] = *reinterpret_cast<const bf16x8*>(bA + ldsOff(wm * 64 + rf * 16 + lr, lg2));
    #pragma unroll
    for (int cf = 0; cf < 4; ++cf)
      bb[cf] = *reinterpret_cast<const bf16x8*>(bA + 8192 + ldsOff(wn * 64 + cf * 16 + lr, lg2));
    __builtin_amdgcn_s_setprio(1);
    #pragma unroll
    for (int rf = 0; rf < 4; ++rf)
      #pragma unroll
      for (int cf = 0; cf < 4; ++cf)
        acc[rf][cf] = __builtin_amdgcn_mfma_f32_16x16x32_bf16(af[rf], bb[cf], acc[rf][cf], 0, 0, 0);
    __builtin_amdgcn_s_setprio(0);
    __builtin_amdgcn_s_barrier();
    asm volatile("" ::: "memory");
    char* tp = bA; bA = bB; bB = bC; bC = tp;
  }
  #pragma unroll
  for (int rf = 0; rf < 4; ++rf)
    #pragma unroll
    for (int cf = 0; cf < 4; ++cf)
      #pragma unroll
      for (int r = 0; r < 4; ++r) {
        int row = wm * 64 + rf * 16 + lg2 * 4 + r;
        int col = wn * 64 + cf * 16 + lr;
        if (routed) {
          int slot = t0 + row;
          if (slot < cntE) {
            int packed = list[(e << 10) + slot];
            int t = packed >> 3, j = packed & 7;
            part[((size_t)t * 6 + j) * 1024 + n0 + col] = f2bf(acc[rf][cf][r]);
          }
        } else {
          out[(size_t)(t0 + row) * HH + n0 + col] = acc[rf][cf][r];
        }
      }
}

__global__ void k_reduce(const us* __restrict__ part, float* __restrict__ out) {
  int i = (blockIdx.x * blockDim.x + threadIdx.x) * 4;
  int t = i >> 10, hh = i & 1023;
  f32x4 s = *reinterpret_cast<const f32x4*>(out + i);   // shared-expert result
  #pragma unroll
  for (int j = 0; j < 6; ++j) {
    us4 p = *reinterpret_cast<const us4*>(part + ((size_t)t * 6 + j) * 1024 + hh);
    #pragma unroll
    for (int k = 0; k < 4; ++k)
      s[k] += __builtin_bit_cast(float, (unsigned)p[k] << 16);
  }
  *reinterpret_cast<f32x4*>(out + i) = s;
}

// ---- workspace layout (total ~102.2 MiB) ----
#define HB_OFF    0ULL
#define CW_OFF    2097152ULL
#define CNT_OFF   2162688ULL
#define SELPK_OFF 2166784ULL
#define LIST_OFF  2170880ULL
#define WLUP_OFF  2236416ULL
#define WLDN_OFF  2244608ULL
#define TOT_OFF   2252800ULL
#define CACTR_OFF 2260992ULL           // 23.07 MB [16*1024][704] bf16
#define CACTS_OFF 25329664ULL          // 4 MB [1024][2048] bf16
#define WGB_OFF   29523968ULL          // 23.07 MB (dead after k_upT)
#define WUB_OFF   52592640ULL          // 23.07 MB (dead after k_upT)
#define SWGB_OFF  75661312ULL          // 4 MB (dead after k_upT)
#define SWUB_OFF  79855616ULL          // 4 MB (dead after k_upT)
#define WDBT_OFF  84049920ULL          // 22.53 MB disjoint (written DURING k_upT)
#define SWDT_OFF  SWGB_OFF             // alias swgb: written by k_tconvS after k_upT
#define PART_OFF  WGB_OFF              // alias wgb: 12 MB [1024][6][1024] bf16

extern "C" void kernel_launch(void* const* d_in, const int* in_sizes, int n_in,
                              void* d_out, int out_size, void* d_ws, size_t ws_size,
                              hipStream_t stream) {
  const float* h    = (const float*)d_in[0];
  const float* gw   = (const float*)d_in[1];
  const float* bias = (const float*)d_in[2];
  const float* wg   = (const float*)d_in[3];
  const float* wu   = (const float*)d_in[4];
  const float* wd   = (const float*)d_in[5];
  const float* swg  = (const float*)d_in[6];
  const float* swu  = (const float*)d_in[7];
  const float* swd  = (const float*)d_in[8];
  float* out = (float*)d_out;

  char* ws = (char*)d_ws;
  us*       hb     = (us*)(ws + HB_OFF);
  float*    cw     = (float*)(ws + CW_OFF);
  int*      cnt    = (int*)(ws + CNT_OFF);
  unsigned* selpk  = (unsigned*)(ws + SELPK_OFF);
  int*      list   = (int*)(ws + LIST_OFF);
  int*      wlUp   = (int*)(ws + WLUP_OFF);
  int*      wlDn   = (int*)(ws + WLDN_OFF);
  int*      totals = (int*)(ws + TOT_OFF);
  us*       cact_r = (us*)(ws + CACTR_OFF);
  us*       cact_s = (us*)(ws + CACTS_OFF);
  us*       wgb    = (us*)(ws + WGB_OFF);
  us*       wub    = (us*)(ws + WUB_OFF);
  us*       swgb   = (us*)(ws + SWGB_OFF);
  us*       swub   = (us*)(ws + SWUB_OFF);
  us*       wdbT   = (us*)(ws + WDBT_OFF);
  us*       swdT   = (us*)(ws + SWDT_OFF);
  us*       part   = (us*)(ws + PART_OFF);

  k_prep<<<7680, 256, 0, stream>>>(h, gw, bias, cw, hb, selpk,
                                   wg, wu, swg, swu, wgb, wub, swgb, swub);
  k_scan<<<1, 1024, 0, stream>>>(selpk, cnt, list, wlUp, wlDn, totals);

  // up-GEMM (128x128 dual, 512 thr) with wd-transpose blocks fused
  k_upT<<<UPMAX + WDTILES, 512, 0, stream>>>(hb, wgb, wub, swgb, swub, cw, list,
                                             cnt, wlUp, totals, cact_r, cact_s,
                                             wd, wdbT);

  k_tconvS<<<512, 256, 0, stream>>>(swd, swdT);   // swdT aliases swgb (now dead)

  k_down<<<DNMAX, 256, 0, stream>>>(cact_r, cact_s, wdbT, swdT, list, cnt,
                                    wlDn, totals, part, out);
  k_reduce<<<1024, 256, 0, stream>>>(part, out);
}

// Round 16
// 130.334 us; speedup vs baseline: 1.2067x; 1.0085x over previous
//
#include <hip/hip_runtime.h>
#include <hip/hip_bf16.h>
#include <math.h>

#define TT 1024
#define HH 1024
#define NEXP 16
#define NI 704
#define SI 2048
#define UPMAX 506             // max active up tiles: 6*63 routed + 128 shared
#define WDTILES 1408          // wd transpose tiles (64r x 128c each) fused into k_up grid
#define DNSHARED 64           // shared down blocks (8 mt x 8 nt, K=2048)
#define DNMAX (DNSHARED + 504)

typedef unsigned short us;
typedef __attribute__((ext_vector_type(8))) __bf16 bf16x8;
typedef __attribute__((ext_vector_type(8))) short s16x8;
typedef __attribute__((ext_vector_type(4))) float f32x4;
typedef __attribute__((ext_vector_type(4))) unsigned short us4;

__device__ __forceinline__ us f2bf(float f) {
  unsigned u = __builtin_bit_cast(unsigned, f);
  u += 0x7fffu + ((u >> 16) & 1u);   // RNE
  return (us)(u >> 16);
}

// Byte offset of 16B chunk (row, kg) in a [rows][32bf16] LDS tile,
// slot swizzle kg' = kg ^ ((row>>1)&3) (2-way residual = free, verified r12).
__device__ __forceinline__ int ldsOff(int row, int kg) {
  return (row * 4 + (kg ^ ((row >> 1) & 3))) * 16;
}

__device__ __forceinline__ void gl16(const void* g, void* l) {
  __builtin_amdgcn_global_load_lds((const __attribute__((address_space(1))) void*)g,
                                   (__attribute__((address_space(3))) void*)l, 16, 0, 0);
}

// m204 bijective XCD-chunk map: blocks with b%8==c process a contiguous
// item chunk -> same-weight tiles stay on one XCD's L2.
__device__ __forceinline__ int chunkMap(int b, int n) {
  int q = n >> 3, r = n & 7;
  int c = b & 7, i = b >> 3;
  int base = (c < r) ? c * (q + 1) : r * (q + 1) + (c - r) * q;
  return base + i;
}

// ---------------- 256-thread transpose+convert tile (64x64) ----------------
// Store side: each 4-lane group writes contiguous 64B per instruction
// (lane rq covers elems [rq*8,rq*8+8) and [32+rq*8,+8) via 16B s16x8 stores).
__device__ __forceinline__ void tconv_tile(const float* __restrict__ inz,
                                           us* __restrict__ outz,
                                           int C, int ldo, int r0, int c0,
                                           float (*tile)[65]) {
  int t = threadIdx.x;
  int rr = t >> 4, cc = (t & 15) * 4;
  #pragma unroll
  for (int i = 0; i < 4; ++i) {
    f32x4 v = *reinterpret_cast<const f32x4*>(inz + (size_t)(r0 + rr + i * 16) * C + c0 + cc);
    tile[rr + i*16][cc + 0] = v[0];
    tile[rr + i*16][cc + 1] = v[1];
    tile[rr + i*16][cc + 2] = v[2];
    tile[rr + i*16][cc + 3] = v[3];
  }
  __syncthreads();
  int c = t >> 2, rq = t & 3;
  us lo[8], hi[8];
  #pragma unroll
  for (int j = 0; j < 8; ++j) {
    lo[j] = f2bf(tile[rq * 8 + j][c]);
    hi[j] = f2bf(tile[32 + rq * 8 + j][c]);
  }
  us* op = outz + (size_t)(c0 + c) * ldo + r0;
  *reinterpret_cast<s16x8*>(op + rq * 8)      = *reinterpret_cast<s16x8*>(&lo[0]);
  *reinterpret_cast<s16x8*>(op + 32 + rq * 8) = *reinterpret_cast<s16x8*>(&hi[0]);
}

// ---------------- 512-thread transpose+convert (64 rows x 128 cols) ----------------
// inz row stride HH; out[(h0+c)*NI + i0+r] = bf16(inz[(i0+r)*HH + h0+c])
__device__ __forceinline__ void tconv512(const float* __restrict__ inz,
                                         us* __restrict__ outz,
                                         int i0, int h0, float (*tile)[129]) {
  int t = threadIdx.x;
  int ir = t >> 3, cg = (t & 7) * 4;
  #pragma unroll
  for (int p = 0; p < 4; ++p) {
    f32x4 v = *reinterpret_cast<const f32x4*>(inz + (size_t)(i0 + ir) * HH + h0 + cg + p * 32);
    tile[ir][cg + p*32 + 0] = v[0];
    tile[ir][cg + p*32 + 1] = v[1];
    tile[ir][cg + p*32 + 2] = v[2];
    tile[ir][cg + p*32 + 3] = v[3];
  }
  __syncthreads();
  int c = t >> 2, rq = t & 3;
  us lo[8], hi[8];
  #pragma unroll
  for (int j = 0; j < 8; ++j) {
    lo[j] = f2bf(tile[rq * 8 + j][c]);
    hi[j] = f2bf(tile[32 + rq * 8 + j][c]);
  }
  us* op = outz + (size_t)(h0 + c) * NI + i0;
  *reinterpret_cast<s16x8*>(op + rq * 8)      = *reinterpret_cast<s16x8*>(&lo[0]);
  *reinterpret_cast<s16x8*>(op + 32 + rq * 8) = *reinterpret_cast<s16x8*>(&hi[0]);
}

// ---------------- prep: gate + h->bf16 + up-weight tconv, fused ----------------
__global__ __launch_bounds__(256) void k_prep(
    const float* __restrict__ h, const float* __restrict__ gw,
    const float* __restrict__ bias, float* __restrict__ cw,
    us* __restrict__ hb, unsigned* __restrict__ selpk,
    const float* __restrict__ wg, const float* __restrict__ wu,
    const float* __restrict__ swg, const float* __restrict__ swu,
    us* __restrict__ wgb, us* __restrict__ wub,
    us* __restrict__ swgb, us* __restrict__ swub) {
  __shared__ float tile[64][65];
  __shared__ float lgS[NEXP];
  int b = blockIdx.x;
  int tid = threadIdx.x;
  if (b < 1024) {
    int t = b;
    const float* hr = h + (size_t)t * HH;
    {
      f32x4 v = *reinterpret_cast<const f32x4*>(hr + tid * 4);
      us4 p;
      p[0] = f2bf(v[0]); p[1] = f2bf(v[1]); p[2] = f2bf(v[2]); p[3] = f2bf(v[3]);
      *reinterpret_cast<us4*>(hb + (size_t)t * HH + tid * 4) = p;
    }
    int e = tid >> 4, sub = tid & 15;
    const f32x4* hr4 = reinterpret_cast<const f32x4*>(hr);
    const f32x4* gr4 = reinterpret_cast<const f32x4*>(gw + (size_t)e * HH);
    float acc = 0.f;
    for (int i = sub; i < 256; i += 16) {
      f32x4 a = hr4[i], g = gr4[i];
      acc += a[0]*g[0] + a[1]*g[1] + a[2]*g[2] + a[3]*g[3];
    }
    acc += __shfl_down(acc, 8, 16);
    acc += __shfl_down(acc, 4, 16);
    acc += __shfl_down(acc, 2, 16);
    acc += __shfl_down(acc, 1, 16);
    if (sub == 0) lgS[e] = acc;
    __syncthreads();
    if (tid == 0) {
      float sc[NEXP], s4[NEXP];
      for (int i = 0; i < NEXP; ++i) {
        sc[i] = 1.f / (1.f + expf(-lgS[i]));
        s4[i] = sc[i] + bias[i];
      }
      float gs[4];
      for (int g = 0; g < 4; ++g) {
        float a = s4[4*g], bb = s4[4*g+1], c = s4[4*g+2], d = s4[4*g+3];
        float mx01 = fmaxf(a, bb), mn01 = fminf(a, bb);
        float mx23 = fmaxf(c, d), mn23 = fminf(c, d);
        float top = fmaxf(mx01, mx23);
        float sec = (mx01 >= mx23) ? fmaxf(mn01, mx23) : fmaxf(mn23, mx01);
        gs[g] = top + sec;
      }
      int g1 = 0;
      for (int g = 1; g < 4; ++g) if (gs[g] > gs[g1]) g1 = g;
      int g2 = -1;
      for (int g = 0; g < 4; ++g) { if (g == g1) continue; if (g2 < 0 || gs[g] > gs[g2]) g2 = g; }
      int sel[6];
      bool used[NEXP];
      for (int i = 0; i < NEXP; ++i) used[i] = false;
      float wsum = 0.f;
      for (int it = 0; it < 6; ++it) {
        int best = -1; float bv = 0.f;
        for (int i = 0; i < NEXP; ++i) {
          int grp = i >> 2;
          if ((grp != g1 && grp != g2) || used[i]) continue;
          if (best < 0 || s4[i] > bv) { best = i; bv = s4[i]; }
        }
        used[best] = true;
        sel[it] = best;
        wsum += sc[best];
      }
      float inv = 2.0f / wsum;   // ROUTED_SCALE folded
      unsigned pk = 0;
      for (int it = 0; it < 6; ++it) {
        pk |= (unsigned)sel[it] << (it * 4);
        cw[(size_t)t * NEXP + sel[it]] = sc[sel[it]] * inv;
      }
      selpk[t] = pk;
    }
    return;
  }
  b -= 1024;
  if (b < 2816) {        // wg: [16][1024 r][704 c] -> wgb [16][704][1024]
    int z = b / 176, r = b % 176;
    tconv_tile(wg + (size_t)z * HH * NI, wgb + (size_t)z * NI * HH,
               NI, HH, (r / 11) * 64, (r % 11) * 64, tile);
    return;
  }
  b -= 2816;
  if (b < 2816) {        // wu
    int z = b / 176, r = b % 176;
    tconv_tile(wu + (size_t)z * HH * NI, wub + (size_t)z * NI * HH,
               NI, HH, (r / 11) * 64, (r % 11) * 64, tile);
    return;
  }
  b -= 2816;
  if (b < 512) {         // swg
    tconv_tile(swg, swgb, SI, HH, (b >> 5) * 64, (b & 31) * 64, tile);
    return;
  }
  b -= 512;
  {                      // swu
    tconv_tile(swu, swub, SI, HH, (b >> 5) * 64, (b & 31) * 64, tile);
  }
}

// ------- deterministic list build + compact work lists (1 block, 16 waves) -------
__global__ void k_scan(const unsigned* __restrict__ selpk,
                       int* __restrict__ cnt, int* __restrict__ list,
                       int* __restrict__ wlUp, int* __restrict__ wlDn,
                       int* __restrict__ totals) {
  int t = threadIdx.x;           // token
  int w = t >> 6, l = t & 63;
  unsigned pk = selpk[t];
  unsigned short flags = 0;
  #pragma unroll
  for (int j = 0; j < 6; ++j) flags |= (unsigned short)(1u << ((pk >> (j * 4)) & 15));
  __shared__ int wc[16][16];
  __shared__ int pre[16][16];
  __shared__ int tiles_s[16], upo[16], dno[16], totR[2];
  #pragma unroll
  for (int e = 0; e < 16; ++e) {
    unsigned long long bal = __ballot((flags >> e) & 1);
    if (l == 0) wc[w][e] = __popcll(bal);
  }
  __syncthreads();
  if (t < 16) {                  // t = expert
    int s = 0;
    for (int ww = 0; ww < 16; ++ww) { pre[ww][t] = s; s += wc[ww][t]; }
    cnt[t] = s;
    tiles_s[t] = (s + 127) >> 7;
  }
  __syncthreads();
  if (t < 16) {
    int uo = 0, dn = 0;
    for (int e2 = 0; e2 < t; ++e2) { uo += 6 * tiles_s[e2]; dn += 8 * tiles_s[e2]; }
    upo[t] = uo; dno[t] = dn;
    if (t == 15) { totR[0] = uo + 6 * tiles_s[15]; totR[1] = dn + 8 * tiles_s[15]; }
  }
  __syncthreads();
  // routed items (wave w = expert w), nt-major (consecutive = same weights)
  {
    int te = tiles_s[w];
    for (int i = l; i < 6 * te; i += 64) {
      int nt = i / te, mt = i - nt * te;
      wlUp[upo[w] + i] = ((w * 6 + nt) << 3) | mt;
    }
    for (int i = l; i < 8 * te; i += 64) {
      int nt = i / te, mt = i - nt * te;
      wlDn[dno[w] + i] = ((w * 8 + nt) << 3) | mt;
    }
  }
  if (w == 0) {
    for (int j = l; j < 128; j += 64)              // shared up appended (16 nt x 8 mt)
      wlUp[totR[0] + j] = ((96 + (j >> 3)) << 3) | (j & 7);
  }
  if (t == 0) { totals[0] = totR[0] + 128; totals[1] = totR[1]; }
  unsigned long long lmask = (l == 0) ? 0ull : ((~0ull) >> (64 - l));
  #pragma unroll
  for (int e = 0; e < 16; ++e) {
    bool f = (flags >> e) & 1;
    unsigned long long bal = __ballot(f);
    if (f) {
      int rank = __popcll(bal & lmask);
      int j = 0;
      #pragma unroll
      for (int jj = 0; jj < 6; ++jj) j += (((pk >> (jj * 4)) & 15) == (unsigned)e) ? jj : 0;
      list[(e << 10) + pre[w][e] + rank] = (t << 3) | j;
    }
  }
}

// ---------------- swd transpose (aliases swgb, runs after k_upT) ----------------
__global__ void k_tconvS(const float* __restrict__ swd, us* __restrict__ swdT) {
  __shared__ float tile[64][65];
  int b = blockIdx.x;            // 512 blocks: [2048 r][1024 c] -> [1024][2048]
  tconv_tile(swd, swdT, HH, SI, (b >> 4) * 64, (b & 15) * 64, tile);
}

// ------- up: 128x128 dual-GEMM, 8 waves, 3-buffer counted-vmcnt + fused wd-tconv -------
__global__ __launch_bounds__(512) void k_upT(
    const us* __restrict__ hb,
    const us* __restrict__ wgb, const us* __restrict__ wub,
    const us* __restrict__ swgb, const us* __restrict__ swub,
    const float* __restrict__ cw, const int* __restrict__ list,
    const int* __restrict__ cnt, const int* __restrict__ wlUp,
    const int* __restrict__ totals,
    us* __restrict__ cact_r, us* __restrict__ cact_s,
    const float* __restrict__ wd, us* __restrict__ wdbT) {
  __shared__ __align__(16) char ldsb[73728];   // 3 x (A 8K | Bg 8K | Bu 8K)
  int tid = threadIdx.x;
  if ((int)blockIdx.x >= UPMAX) {
    // fused wd transpose: [16][704 r][1024 c] -> wdbT [16][1024][704]
    int b = blockIdx.x - UPMAX;
    int z = b / 88, r = b % 88;
    tconv512(wd + (size_t)z * NI * HH, wdbT + (size_t)z * HH * NI,
             (r >> 3) * 64, (r & 7) * 128,
             reinterpret_cast<float(*)[129]>(ldsb));
    return;
  }
  int tot = totals[0];
  if ((int)blockIdx.x >= tot) return;
  int item = wlUp[chunkMap(blockIdx.x, tot)];
  int group = item >> 3, mt = item & 7;
  int t0 = mt * 128;
  bool routed = group < 96;
  int e = 0, n0, cntE = TT;
  const us *bgBase, *buBase;
  if (routed) {
    e = group / 6;
    n0 = (group - e * 6) * 128;
    cntE = cnt[e];
    bgBase = wgb + (size_t)e * NI * HH;
    buBase = wub + (size_t)e * NI * HH;
  } else {
    n0 = (group - 96) * 128;
    bgBase = swgb;
    buBase = swub;
  }
  int w = tid >> 6, l = tid & 63;
  int wm = w >> 2, wn = w & 3;      // 2 (M) x 4 (N) wave grid
  int lr = l & 15, lg2 = l >> 4;

  int rowA = tid >> 2;              // 0..127 (1 chunk/thread per matrix)
  int kg = (tid & 3) ^ ((rowA >> 1) & 3);
  int tok = t0 + rowA;
  if (routed) tok = (tok < cntE) ? (list[(e << 10) + tok] >> 3) : 0;
  int bRow = n0 + rowA;
  if (routed && bRow >= NI) bRow = NI - 1;   // clamp edge N-tile (n0=640)
  const us* aS = hb + (size_t)tok * HH + kg * 8;
  const us* gS = bgBase + (size_t)bRow * HH + kg * 8;
  const us* uS = buBase + (size_t)bRow * HH + kg * 8;

  f32x4 accG[4][2] = {};
  f32x4 accU[4][2] = {};

  int wslot = w * 1024;
  auto stage = [&](char* buf) {     // 3 gl_lds per thread, then advance
    char* b = buf + wslot;          // wave-uniform dest + lane*16
    gl16(aS, b);
    gl16(gS, b + 8192);
    gl16(uS, b + 16384);
    aS += 32; gS += 32; uS += 32;
  };

  char* bA = ldsb;
  char* bB = ldsb + 24576;
  char* bC = ldsb + 49152;
  stage(bA);                        // k-step 0
  stage(bB);                        // k-step 1
  for (int ki = 0; ki < 32; ++ki) {
    if (ki < 30) {
      stage(bC);                                            // depth-2 prefetch
      asm volatile("s_waitcnt vmcnt(6)" ::: "memory");      // stage(ki) landed
    } else if (ki == 30) {
      asm volatile("s_waitcnt vmcnt(3)" ::: "memory");
    } else {
      asm volatile("s_waitcnt vmcnt(0)" ::: "memory");
    }
    __builtin_amdgcn_s_barrier();
    asm volatile("" ::: "memory");
    bf16x8 af[4], bg[2], bu[2];
    #pragma unroll
    for (int rf = 0; rf < 4; ++rf)
      af[rf] = *reinterpret_cast<const bf16x8*>(bA + ldsOff(wm * 64 + rf * 16 + lr, lg2));
    #pragma unroll
    for (int cf = 0; cf < 2; ++cf) {
      int n = wn * 32 + cf * 16 + lr;
      bg[cf] = *reinterpret_cast<const bf16x8*>(bA + 8192  + ldsOff(n, lg2));
      bu[cf] = *reinterpret_cast<const bf16x8*>(bA + 16384 + ldsOff(n, lg2));
    }
    __builtin_amdgcn_s_setprio(1);
    #pragma unroll
    for (int rf = 0; rf < 4; ++rf)
      #pragma unroll
      for (int cf = 0; cf < 2; ++cf) {
        accG[rf][cf] = __builtin_amdgcn_mfma_f32_16x16x32_bf16(af[rf], bg[cf], accG[rf][cf], 0, 0, 0);
        accU[rf][cf] = __builtin_amdgcn_mfma_f32_16x16x32_bf16(af[rf], bu[cf], accU[rf][cf], 0, 0, 0);
      }
    __builtin_amdgcn_s_setprio(0);
    __builtin_amdgcn_s_barrier();
    asm volatile("" ::: "memory");
    char* tp = bA; bA = bB; bB = bC; bC = tp;               // rotate (no indexing)
  }
  #pragma unroll
  for (int rf = 0; rf < 4; ++rf)
    #pragma unroll
    for (int cf = 0; cf < 2; ++cf)
      #pragma unroll
      for (int r = 0; r < 4; ++r) {
        int row = wm * 64 + rf * 16 + lg2 * 4 + r;
        int col = wn * 32 + cf * 16 + lr;
        float g = accG[rf][cf][r], u = accU[rf][cf][r];
        float act = g / (1.f + __expf(-g)) * u;
        if (routed) {
          int slot = t0 + row;
          if (slot < cntE && n0 + col < NI) {
            int packed = list[(e << 10) + slot];
            float scl = cw[(size_t)(packed >> 3) * NEXP + e];
            cact_r[((size_t)(e << 10) + slot) * NI + n0 + col] = f2bf(act * scl);
          }
        } else {
          cact_s[(size_t)(t0 + row) * SI + n0 + col] = f2bf(act);
        }
      }
}

// ------- down: 3-buffer counted-vmcnt; [0,64) shared K=2048 -> out; rest routed -> bf16 part -------
__global__ __launch_bounds__(256) void k_down(
    const us* __restrict__ cact_r, const us* __restrict__ cact_s,
    const us* __restrict__ wdbT, const us* __restrict__ swdT,
    const int* __restrict__ list, const int* __restrict__ cnt,
    const int* __restrict__ wlDn, const int* __restrict__ totals,
    us* __restrict__ part, float* __restrict__ out) {
  __shared__ __align__(16) char ldsb[49152];   // 3 x (A 8K | B 8K)
  int tid = threadIdx.x;
  int b = blockIdx.x;
  bool routed;
  int e = 0, nt, mt, kiter, Ksrc, cntE = TT;
  const us *Ab, *Bb;
  if (b < DNSHARED) {
    routed = false;
    nt = b & 7;
    mt = b >> 3;
    kiter = 64;                 // full K=2048
    Ksrc = SI;
    Ab = cact_s;
    Bb = swdT;
  } else {
    routed = true;
    int rb = b - DNSHARED;
    int tot = totals[1];
    if (rb >= tot) return;
    int item = wlDn[chunkMap(rb, tot)];
    int group = item >> 3;
    mt = item & 7;
    e = group >> 3; nt = group & 7;
    cntE = cnt[e];
    kiter = NI / 32;            // 22
    Ksrc = NI;
    Ab = cact_r + (size_t)e * 1024 * NI;
    Bb = wdbT + (size_t)e * 1024 * NI;
  }
  int t0 = mt * 128;
  int n0 = nt * 128;
  int w = tid >> 6, l = tid & 63;
  int wm = w >> 1, wn = w & 1;
  int lr = l & 15, lg2 = l >> 4;

  int rowA = tid >> 2;
  int kg = (tid & 3) ^ ((rowA >> 1) & 3);
  const us* aS0 = Ab + (size_t)(t0 + rowA) * Ksrc + kg * 8;
  const us* aS1 = Ab + (size_t)(t0 + 64 + rowA) * Ksrc + kg * 8;
  const us* bS0 = Bb + (size_t)(n0 + rowA) * Ksrc + kg * 8;
  const us* bS1 = Bb + (size_t)(n0 + 64 + rowA) * Ksrc + kg * 8;

  f32x4 acc[4][4] = {};

  int wslot = w * 1024;
  auto stage = [&](char* buf) {
    char* bp = buf + wslot;
    gl16(aS0, bp);
    gl16(aS1, bp + 4096);
    gl16(bS0, bp + 8192);
    gl16(bS1, bp + 12288);
    aS0 += 32; aS1 += 32; bS0 += 32; bS1 += 32;
  };

  char* bA = ldsb;
  char* bB = ldsb + 16384;
  char* bC = ldsb + 32768;
  stage(bA);
  stage(bB);
  for (int ki = 0; ki < kiter; ++ki) {
    if (ki + 2 < kiter) {
      stage(bC);                                            // depth-2 prefetch
      asm volatile("s_waitcnt vmcnt(8)" ::: "memory");      // stage(ki) landed
    } else if (ki + 2 == kiter) {
      asm volatile("s_waitcnt vmcnt(4)" ::: "memory");
    } else {
      asm volatile("s_waitcnt vmcnt(0)" ::: "memory");
    }
    __builtin_amdgcn_s_barrier();
    asm volatile("" ::: "memory");
    bf16x8 af[4], bb[4];
    #pragma unroll
    for (int rf = 0; rf < 4; ++rf)
      af[rf] = *reinterpret_cast<const bf16x8*>(bA + ldsOff(wm * 64 + rf * 16 + lr, lg2));
    #pragma unroll
    for (int cf = 0; cf < 4; ++cf)
      bb[cf] = *reinterpret_cast<const bf16x8*>(bA + 8192 + ldsOff(wn * 64 + cf * 16 + lr, lg2));
    __builtin_amdgcn_s_setprio(1);
    #pragma unroll
    for (int rf = 0; rf < 4; ++rf)
      #pragma unroll
      for (int cf = 0; cf < 4; ++cf)
        acc[rf][cf] = __builtin_amdgcn_mfma_f32_16x16x32_bf16(af[rf], bb[cf], acc[rf][cf], 0, 0, 0);
    __builtin_amdgcn_s_setprio(0);
    __builtin_amdgcn_s_barrier();
    asm volatile("" ::: "memory");
    char* tp = bA; bA = bB; bB = bC; bC = tp;
  }
  #pragma unroll
  for (int rf = 0; rf < 4; ++rf)
    #pragma unroll
    for (int cf = 0; cf < 4; ++cf)
      #pragma unroll
      for (int r = 0; r < 4; ++r) {
        int row = wm * 64 + rf * 16 + lg2 * 4 + r;
        int col = wn * 64 + cf * 16 + lr;
        if (routed) {
          int slot = t0 + row;
          if (slot < cntE) {
            int packed = list[(e << 10) + slot];
            int t = packed >> 3, j = packed & 7;
            part[((size_t)t * 6 + j) * 1024 + n0 + col] = f2bf(acc[rf][cf][r]);
          }
        } else {
          out[(size_t)(t0 + row) * HH + n0 + col] = acc[rf][cf][r];
        }
      }
}

__global__ void k_reduce(const us* __restrict__ part, float* __restrict__ out) {
  int i = (blockIdx.x * blockDim.x + threadIdx.x) * 4;
  int t = i >> 10, hh = i & 1023;
  f32x4 s = *reinterpret_cast<const f32x4*>(out + i);   // shared-expert result
  #pragma unroll
  for (int j = 0; j < 6; ++j) {
    us4 p = *reinterpret_cast<const us4*>(part + ((size_t)t * 6 + j) * 1024 + hh);
    #pragma unroll
    for (int k = 0; k < 4; ++k)
      s[k] += __builtin_bit_cast(float, (unsigned)p[k] << 16);
  }
  *reinterpret_cast<f32x4*>(out + i) = s;
}

// ---- workspace layout (total ~102.2 MiB) ----
#define HB_OFF    0ULL
#define CW_OFF    2097152ULL
#define CNT_OFF   2162688ULL
#define SELPK_OFF 2166784ULL
#define LIST_OFF  2170880ULL
#define WLUP_OFF  2236416ULL
#define WLDN_OFF  2244608ULL
#define TOT_OFF   2252800ULL
#define CACTR_OFF 2260992ULL           // 23.07 MB [16*1024][704] bf16
#define CACTS_OFF 25329664ULL          // 4 MB [1024][2048] bf16
#define WGB_OFF   29523968ULL          // 23.07 MB (dead after k_upT)
#define WUB_OFF   52592640ULL          // 23.07 MB (dead after k_upT)
#define SWGB_OFF  75661312ULL          // 4 MB (dead after k_upT)
#define SWUB_OFF  79855616ULL          // 4 MB (dead after k_upT)
#define WDBT_OFF  84049920ULL          // 22.53 MB disjoint (written DURING k_upT)
#define SWDT_OFF  SWGB_OFF             // alias swgb: written by k_tconvS after k_upT
#define PART_OFF  WGB_OFF              // alias wgb: 12 MB [1024][6][1024] bf16

extern "C" void kernel_launch(void* const* d_in, const int* in_sizes, int n_in,
                              void* d_out, int out_size, void* d_ws, size_t ws_size,
                              hipStream_t stream) {
  const float* h    = (const float*)d_in[0];
  const float* gw   = (const float*)d_in[1];
  const float* bias = (const float*)d_in[2];
  const float* wg   = (const float*)d_in[3];
  const float* wu   = (const float*)d_in[4];
  const float* wd   = (const float*)d_in[5];
  const float* swg  = (const float*)d_in[6];
  const float* swu  = (const float*)d_in[7];
  const float* swd  = (const float*)d_in[8];
  float* out = (float*)d_out;

  char* ws = (char*)d_ws;
  us*       hb     = (us*)(ws + HB_OFF);
  float*    cw     = (float*)(ws + CW_OFF);
  int*      cnt    = (int*)(ws + CNT_OFF);
  unsigned* selpk  = (unsigned*)(ws + SELPK_OFF);
  int*      list   = (int*)(ws + LIST_OFF);
  int*      wlUp   = (int*)(ws + WLUP_OFF);
  int*      wlDn   = (int*)(ws + WLDN_OFF);
  int*      totals = (int*)(ws + TOT_OFF);
  us*       cact_r = (us*)(ws + CACTR_OFF);
  us*       cact_s = (us*)(ws + CACTS_OFF);
  us*       wgb    = (us*)(ws + WGB_OFF);
  us*       wub    = (us*)(ws + WUB_OFF);
  us*       swgb   = (us*)(ws + SWGB_OFF);
  us*       swub   = (us*)(ws + SWUB_OFF);
  us*       wdbT   = (us*)(ws + WDBT_OFF);
  us*       swdT   = (us*)(ws + SWDT_OFF);
  us*       part   = (us*)(ws + PART_OFF);

  k_prep<<<7680, 256, 0, stream>>>(h, gw, bias, cw, hb, selpk,
                                   wg, wu, swg, swu, wgb, wub, swgb, swub);
  k_scan<<<1, 1024, 0, stream>>>(selpk, cnt, list, wlUp, wlDn, totals);

  // up-GEMM (128x128 dual, 512 thr) with wd-transpose blocks fused
  k_upT<<<UPMAX + WDTILES, 512, 0, stream>>>(hb, wgb, wub, swgb, swub, cw, list,
                                             cnt, wlUp, totals, cact_r, cact_s,
                                             wd, wdbT);

  k_tconvS<<<512, 256, 0, stream>>>(swd, swdT);   // swdT aliases swgb (now dead)

  k_down<<<DNMAX, 256, 0, stream>>>(cact_r, cact_s, wdbT, swdT, list, cnt,
                                    wlDn, totals, part, out);
  k_reduce<<<1024, 256, 0, stream>>>(part, out);
}